// Round 1
// baseline (1071.213 us; speedup 1.0000x reference)
//
#include <hip/hip_runtime.h>
#include <hip/hip_bf16.h>

#define NN 50000
#define NE 800000
#define FIN 128
#define DD 64
#define NHEADS 3
#define NG 1024
#define HD 192

// ---------------- zero fill ----------------
__global__ __launch_bounds__(256) void zero_kernel(unsigned int* __restrict__ p, int nwords) {
    int i = blockIdx.x * 256 + threadIdx.x;
    if (i < nwords) p[i] = 0u;
}

// ---------------- GEMM: C[nrows,M] = A[nrows,K] @ B[K,M] (+bias) ----------------
// block = 256 threads, 64 rows per block. wave w handles rows w*16..w*16+15,
// lane -> column lane + h*64. A tile staged in LDS row-major; A reads are
// wave-uniform broadcast ds_read_b128 (conflict-free). B read from L2 (tiny).
template<int K, int M, bool BIAS>
__global__ __launch_bounds__(256) void gemm_kernel(const float* __restrict__ A,
                                                   const float* __restrict__ B,
                                                   const float* __restrict__ bias,
                                                   float* __restrict__ C, int nrows) {
    constexpr int NH = M / 64;
    __shared__ float As[64 * K];
    const int tid = threadIdx.x;
    const int row0 = blockIdx.x * 64;

    for (int idx = tid; idx < 64 * (K / 4); idx += 256) {
        int r = idx / (K / 4);
        int k4 = idx - r * (K / 4);
        float4 v = make_float4(0.f, 0.f, 0.f, 0.f);
        if (row0 + r < nrows) v = *(const float4*)(A + (size_t)(row0 + r) * K + k4 * 4);
        *(float4*)(&As[r * K + k4 * 4]) = v;
    }
    __syncthreads();

    const int lane = tid & 63;
    const int wid = tid >> 6;

    float acc[16][NH];
#pragma unroll
    for (int i = 0; i < 16; ++i)
#pragma unroll
        for (int h = 0; h < NH; ++h) acc[i][h] = 0.f;

    for (int k0 = 0; k0 < K; k0 += 4) {
        float bv[4][NH];
#pragma unroll
        for (int j = 0; j < 4; ++j)
#pragma unroll
            for (int h = 0; h < NH; ++h)
                bv[j][h] = B[(k0 + j) * M + h * 64 + lane];
#pragma unroll
        for (int i = 0; i < 16; ++i) {
            float4 a = *(const float4*)(&As[(wid * 16 + i) * K + k0]);
#pragma unroll
            for (int h = 0; h < NH; ++h) {
                acc[i][h] = fmaf(a.x, bv[0][h], acc[i][h]);
                acc[i][h] = fmaf(a.y, bv[1][h], acc[i][h]);
                acc[i][h] = fmaf(a.z, bv[2][h], acc[i][h]);
                acc[i][h] = fmaf(a.w, bv[3][h], acc[i][h]);
            }
        }
    }

#pragma unroll
    for (int i = 0; i < 16; ++i) {
        int r = row0 + wid * 16 + i;
        if (r < nrows) {
#pragma unroll
            for (int h = 0; h < NH; ++h) {
                float v = acc[i][h];
                if (BIAS) v += bias[h * 64 + lane];
                C[(size_t)r * M + h * 64 + lane] = v;
            }
        }
    }
}

// ---------------- el/er: el[n,h] = sum_d z[n,h,d]*al[h,d] ----------------
__global__ __launch_bounds__(256) void attn_kernel(const float* __restrict__ z,
                                                   const float* __restrict__ al,
                                                   const float* __restrict__ ar,
                                                   float* __restrict__ el,
                                                   float* __restrict__ er) {
    int node = blockIdx.x * 4 + (threadIdx.x >> 6);
    int lane = threadIdx.x & 63;
    if (node >= NN) return;
#pragma unroll
    for (int h = 0; h < NHEADS; ++h) {
        float zv = z[(size_t)node * HD + h * 64 + lane];
        float pl = zv * al[h * 64 + lane];
        float pr = zv * ar[h * 64 + lane];
#pragma unroll
        for (int off = 32; off > 0; off >>= 1) {
            pl += __shfl_xor(pl, off);
            pr += __shfl_xor(pr, off);
        }
        if (lane == 0) {
            el[node * NHEADS + h] = pl;
            er[node * NHEADS + h] = pr;
        }
    }
}

// ---------------- CSR build ----------------
__global__ __launch_bounds__(256) void count_kernel(const int* __restrict__ dst, int* __restrict__ cnt) {
    int e = blockIdx.x * 256 + threadIdx.x;
    if (e < NE) atomicAdd(&cnt[dst[e]], 1);
}

__global__ __launch_bounds__(256) void scan_block_kernel(const int* __restrict__ cnt,
                                                         int* __restrict__ incl,
                                                         int* __restrict__ bsum, int n) {
    __shared__ int s[256];
    int tid = threadIdx.x;
    int i = blockIdx.x * 256 + tid;
    int v = (i < n) ? cnt[i] : 0;
    s[tid] = v;
    __syncthreads();
#pragma unroll
    for (int off = 1; off < 256; off <<= 1) {
        int add = (tid >= off) ? s[tid - off] : 0;
        __syncthreads();
        s[tid] += add;
        __syncthreads();
    }
    if (i < n) incl[i] = s[tid];
    if (tid == 255) bsum[blockIdx.x] = s[255];
}

__global__ __launch_bounds__(256) void scan_bsum_kernel(int* __restrict__ bsum, int nb) {
    __shared__ int s[256];
    int tid = threadIdx.x;
    int v = (tid < nb) ? bsum[tid] : 0;
    s[tid] = v;
    __syncthreads();
#pragma unroll
    for (int off = 1; off < 256; off <<= 1) {
        int add = (tid >= off) ? s[tid - off] : 0;
        __syncthreads();
        s[tid] += add;
        __syncthreads();
    }
    if (tid < nb) bsum[tid] = s[tid] - v;  // exclusive
}

__global__ __launch_bounds__(256) void finalize_rowptr_kernel(const int* __restrict__ incl,
                                                              const int* __restrict__ boff,
                                                              int* __restrict__ row_ptr, int n) {
    int i = blockIdx.x * 256 + threadIdx.x;
    if (i < n) row_ptr[i + 1] = incl[i] + boff[i >> 8];
    if (i == 0) row_ptr[0] = 0;
}

__global__ __launch_bounds__(256) void fill_kernel(const int* __restrict__ src,
                                                   const int* __restrict__ dst,
                                                   const int* __restrict__ row_ptr,
                                                   int* __restrict__ cur,
                                                   int* __restrict__ srcs_sorted) {
    int e = blockIdx.x * 256 + threadIdx.x;
    if (e < NE) {
        int d = dst[e];
        int pos = row_ptr[d] + atomicAdd(&cur[d], 1);
        srcs_sorted[pos] = src[e];
    }
}

// ---------------- aggregation: one wave per dst node ----------------
__global__ __launch_bounds__(256) void aggregate_kernel(const float* __restrict__ z,
                                                        const float* __restrict__ el,
                                                        const float* __restrict__ er,
                                                        const int* __restrict__ row_ptr,
                                                        const int* __restrict__ srcs,
                                                        const float* __restrict__ bias,
                                                        float* __restrict__ y) {
    int node = blockIdx.x * 4 + (threadIdx.x >> 6);
    int lane = threadIdx.x & 63;
    if (node >= NN) return;
    int s0 = row_ptr[node], s1 = row_ptr[node + 1];
    size_t o = (size_t)node * HD;
    if (s1 <= s0) {  // cannot happen (self-loops) but keep safe
        y[o + lane] = bias[lane];
        y[o + 64 + lane] = bias[64 + lane];
        y[o + 128 + lane] = bias[128 + lane];
        return;
    }
    float er0 = er[node * 3 + 0], er1 = er[node * 3 + 1], er2 = er[node * 3 + 2];

    float m0 = -1e30f, m1 = -1e30f, m2 = -1e30f;
    for (int i = s0; i < s1; ++i) {
        int s = srcs[i];
        float e0 = el[s * 3 + 0] + er0;
        float e1 = el[s * 3 + 1] + er1;
        float e2 = el[s * 3 + 2] + er2;
        e0 = e0 > 0.f ? e0 : 0.2f * e0;
        e1 = e1 > 0.f ? e1 : 0.2f * e1;
        e2 = e2 > 0.f ? e2 : 0.2f * e2;
        m0 = fmaxf(m0, e0);
        m1 = fmaxf(m1, e1);
        m2 = fmaxf(m2, e2);
    }
    float d0 = 0.f, d1 = 0.f, d2 = 0.f;
    float a0 = 0.f, a1 = 0.f, a2 = 0.f;
    for (int i = s0; i < s1; ++i) {
        int s = srcs[i];
        float e0 = el[s * 3 + 0] + er0;
        float e1 = el[s * 3 + 1] + er1;
        float e2 = el[s * 3 + 2] + er2;
        e0 = e0 > 0.f ? e0 : 0.2f * e0;
        e1 = e1 > 0.f ? e1 : 0.2f * e1;
        e2 = e2 > 0.f ? e2 : 0.2f * e2;
        float p0 = __expf(e0 - m0);
        float p1 = __expf(e1 - m1);
        float p2 = __expf(e2 - m2);
        d0 += p0; d1 += p1; d2 += p2;
        const float* zr = z + (size_t)s * HD;
        a0 = fmaf(p0, zr[lane], a0);
        a1 = fmaf(p1, zr[64 + lane], a1);
        a2 = fmaf(p2, zr[128 + lane], a2);
    }
    y[o + lane] = a0 / d0 + bias[lane];
    y[o + 64 + lane] = a1 / d1 + bias[64 + lane];
    y[o + 128 + lane] = a2 / d2 + bias[128 + lane];
}

// ---------------- pooling ----------------
__global__ __launch_bounds__(256) void pool_accum_kernel(const float* __restrict__ x,
                                                         const int* __restrict__ gid,
                                                         float* __restrict__ gsum,
                                                         int* __restrict__ gcnt) {
    int idx = blockIdx.x * 256 + threadIdx.x;
    int node = idx >> 6;
    int d = idx & 63;
    if (node < NN) {
        int g = gid[node];
        atomicAdd(&gsum[g * 64 + d], x[(size_t)node * 64 + d]);
        if (d == 0) atomicAdd(&gcnt[g], 1);
    }
}

__global__ __launch_bounds__(256) void pool_final_kernel(const float* __restrict__ gsum,
                                                         const int* __restrict__ gcnt,
                                                         float* __restrict__ out) {
    int idx = blockIdx.x * 256 + threadIdx.x;
    if (idx < NG * 64) {
        int g = idx >> 6;
        float c = (float)gcnt[g];
        out[idx] = gsum[idx] / fmaxf(c, 1.0f);
    }
}

// ---------------- launch ----------------
extern "C" void kernel_launch(void* const* d_in, const int* in_sizes, int n_in,
                              void* d_out, int out_size, void* d_ws, size_t ws_size,
                              hipStream_t stream) {
    const float* feats = (const float*)d_in[0];
    const int* src = (const int*)d_in[1];
    const int* dst = (const int*)d_in[2];
    const int* gid = (const int*)d_in[3];
    const float* W1 = (const float*)d_in[4];
    const float* al1 = (const float*)d_in[5];
    const float* ar1 = (const float*)d_in[6];
    const float* b1 = (const float*)d_in[7];
    const float* W2 = (const float*)d_in[8];
    const float* al2 = (const float*)d_in[9];
    const float* ar2 = (const float*)d_in[10];
    const float* b2 = (const float*)d_in[11];
    const float* Wl = (const float*)d_in[12];
    const float* bl = (const float*)d_in[13];
    float* out = (float*)d_out;

    // workspace layout
    size_t off = 0;
    auto alloc = [&](size_t bytes) -> char* {
        char* p = (char*)d_ws + off;
        off += (bytes + 255) & ~(size_t)255;
        return p;
    };
    float* z = (float*)alloc((size_t)NN * HD * 4);
    float* y = (float*)alloc((size_t)NN * HD * 4);
    float* x = (float*)alloc((size_t)NN * 64 * 4);
    float* el = (float*)alloc((size_t)NN * 3 * 4);
    float* er = (float*)alloc((size_t)NN * 3 * 4);
    int* row_ptr = (int*)alloc((size_t)(NN + 1) * 4);
    int* cnt = (int*)alloc((size_t)NN * 4);
    int* incl = (int*)alloc((size_t)NN * 4);
    int* bsum = (int*)alloc(256 * 4);
    int* srcs = (int*)alloc((size_t)NE * 4);
    float* gsum = (float*)alloc((size_t)NG * 64 * 4);
    int* gcnt = (int*)alloc((size_t)NG * 4);  // contiguous after gsum

    const int nbScan = (NN + 255) / 256;  // 196
    const int gridE = (NE + 255) / 256;   // 3125
    const int gridNode = (NN + 3) / 4;    // 12501
    const int gridGemm = (NN + 63) / 64;  // 782

    // ---- CSR build (once; shared by all 3 convs) ----
    zero_kernel<<<(NN + 255) / 256, 256, 0, stream>>>((unsigned int*)cnt, NN);
    count_kernel<<<gridE, 256, 0, stream>>>(dst, cnt);
    scan_block_kernel<<<nbScan, 256, 0, stream>>>(cnt, incl, bsum, NN);
    scan_bsum_kernel<<<1, 256, 0, stream>>>(bsum, nbScan);
    finalize_rowptr_kernel<<<nbScan, 256, 0, stream>>>(incl, bsum, row_ptr, NN);
    zero_kernel<<<(NN + 255) / 256, 256, 0, stream>>>((unsigned int*)cnt, NN);
    fill_kernel<<<gridE, 256, 0, stream>>>(src, dst, row_ptr, cnt, srcs);

    // ---- conv1: feats @ W1 ----
    gemm_kernel<FIN, HD, false><<<gridGemm, 256, 0, stream>>>(feats, W1, nullptr, z, NN);
    attn_kernel<<<gridNode, 256, 0, stream>>>(z, al1, ar1, el, er);
    aggregate_kernel<<<gridNode, 256, 0, stream>>>(z, el, er, row_ptr, srcs, b1, y);
    gemm_kernel<HD, 64, true><<<gridGemm, 256, 0, stream>>>(y, Wl, bl, x, NN);

    // ---- conv2, conv3 ----
    for (int it = 0; it < 2; ++it) {
        gemm_kernel<64, HD, false><<<gridGemm, 256, 0, stream>>>(x, W2, nullptr, z, NN);
        attn_kernel<<<gridNode, 256, 0, stream>>>(z, al2, ar2, el, er);
        aggregate_kernel<<<gridNode, 256, 0, stream>>>(z, el, er, row_ptr, srcs, b2, y);
        gemm_kernel<HD, 64, true><<<gridGemm, 256, 0, stream>>>(y, Wl, bl, x, NN);
    }

    // ---- avg pooling ----
    zero_kernel<<<(NG * 64 + NG + 255) / 256, 256, 0, stream>>>((unsigned int*)gsum, NG * 64 + NG);
    pool_accum_kernel<<<(NN * 64) / 256, 256, 0, stream>>>(x, gid, gsum, gcnt);
    pool_final_kernel<<<(NG * 64 + 255) / 256, 256, 0, stream>>>(gsum, gcnt, out);
}

// Round 3
// 780.578 us; speedup vs baseline: 1.3723x; 1.3723x over previous
//
#include <hip/hip_runtime.h>
#include <hip/hip_bf16.h>

#define NN 50000
#define NE 800000
#define FIN 128
#define DD 64
#define NHEADS 3
#define NG 1024
#define HD 192

typedef unsigned short ushort_t;

__device__ __forceinline__ float bf2f(ushort_t u) {
    union { unsigned int i; float f; } c;
    c.i = ((unsigned int)u) << 16;
    return c.f;
}
__device__ __forceinline__ ushort_t f2bf(float f) {
    __hip_bfloat16 h = __float2bfloat16(f);
    return *reinterpret_cast<ushort_t*>(&h);
}

// ---------------- GEMM: C[nrows,M] = A[nrows,K] @ B[K,M] ----------------
// block = 256 threads, 64 rows per block; wave w -> rows w*16..+15, lane -> col h*64+lane.
// ATTN: also compute el/er via wave reduction against al/ar; output z as bf16.
// !ATTN: add bias, output f32.
template<int K, int M, bool ATTN>
__global__ __launch_bounds__(256) void gemm_kernel(const float* __restrict__ A,
                                                   const float* __restrict__ B,
                                                   const float* __restrict__ bias,
                                                   const float* __restrict__ al,
                                                   const float* __restrict__ ar,
                                                   float* __restrict__ el,
                                                   float* __restrict__ er,
                                                   float* __restrict__ Cf,
                                                   ushort_t* __restrict__ Cb,
                                                   int nrows) {
    constexpr int NH = M / 64;
    __shared__ float As[64 * K];
    const int tid = threadIdx.x;
    const int row0 = blockIdx.x * 64;

    for (int idx = tid; idx < 64 * (K / 4); idx += 256) {
        int r = idx / (K / 4);
        int k4 = idx - r * (K / 4);
        float4 v = make_float4(0.f, 0.f, 0.f, 0.f);
        if (row0 + r < nrows) v = *(const float4*)(A + (size_t)(row0 + r) * K + k4 * 4);
        *(float4*)(&As[r * K + k4 * 4]) = v;
    }
    __syncthreads();

    const int lane = tid & 63;
    const int wid = tid >> 6;

    float acc[16][NH];
#pragma unroll
    for (int i = 0; i < 16; ++i)
#pragma unroll
        for (int h = 0; h < NH; ++h) acc[i][h] = 0.f;

    for (int k0 = 0; k0 < K; k0 += 4) {
        float bv[4][NH];
#pragma unroll
        for (int j = 0; j < 4; ++j)
#pragma unroll
            for (int h = 0; h < NH; ++h)
                bv[j][h] = B[(k0 + j) * M + h * 64 + lane];
#pragma unroll
        for (int i = 0; i < 16; ++i) {
            float4 a = *(const float4*)(&As[(wid * 16 + i) * K + k0]);
#pragma unroll
            for (int h = 0; h < NH; ++h) {
                acc[i][h] = fmaf(a.x, bv[0][h], acc[i][h]);
                acc[i][h] = fmaf(a.y, bv[1][h], acc[i][h]);
                acc[i][h] = fmaf(a.z, bv[2][h], acc[i][h]);
                acc[i][h] = fmaf(a.w, bv[3][h], acc[i][h]);
            }
        }
    }

    if (ATTN) {
        float alv[NH], arv[NH];
#pragma unroll
        for (int h = 0; h < NH; ++h) {
            alv[h] = al[h * 64 + lane];
            arv[h] = ar[h * 64 + lane];
        }
#pragma unroll
        for (int i = 0; i < 16; ++i) {
            int r = row0 + wid * 16 + i;
            bool valid = (r < nrows);
#pragma unroll
            for (int h = 0; h < NH; ++h) {
                float pl = acc[i][h] * alv[h];
                float pr = acc[i][h] * arv[h];
#pragma unroll
                for (int off = 32; off > 0; off >>= 1) {
                    pl += __shfl_xor(pl, off);
                    pr += __shfl_xor(pr, off);
                }
                if (valid) {
                    Cb[(size_t)r * M + h * 64 + lane] = f2bf(acc[i][h]);
                    if (lane == 0) {
                        el[r * NHEADS + h] = pl;
                        er[r * NHEADS + h] = pr;
                    }
                }
            }
        }
    } else {
#pragma unroll
        for (int i = 0; i < 16; ++i) {
            int r = row0 + wid * 16 + i;
            if (r < nrows) {
#pragma unroll
                for (int h = 0; h < NH; ++h)
                    Cf[(size_t)r * M + h * 64 + lane] = acc[i][h] + bias[h * 64 + lane];
            }
        }
    }
}

// ---------------- CSR build ----------------
__global__ __launch_bounds__(256) void count_kernel(const int* __restrict__ dst, int* __restrict__ cnt) {
    int e = blockIdx.x * 256 + threadIdx.x;
    if (e < NE) atomicAdd(&cnt[dst[e]], 1);
}

__global__ __launch_bounds__(256) void scan_block_kernel(const int* __restrict__ cnt,
                                                         int* __restrict__ incl,
                                                         int* __restrict__ bsum, int n) {
    __shared__ int s[256];
    int tid = threadIdx.x;
    int i = blockIdx.x * 256 + tid;
    int v = (i < n) ? cnt[i] : 0;
    s[tid] = v;
    __syncthreads();
#pragma unroll
    for (int off = 1; off < 256; off <<= 1) {
        int add = (tid >= off) ? s[tid - off] : 0;
        __syncthreads();
        s[tid] += add;
        __syncthreads();
    }
    if (i < n) incl[i] = s[tid];
    if (tid == 255) bsum[blockIdx.x] = s[255];
}

__global__ __launch_bounds__(256) void scan_bsum_kernel(int* __restrict__ bsum, int nb) {
    __shared__ int s[256];
    int tid = threadIdx.x;
    int v = (tid < nb) ? bsum[tid] : 0;
    s[tid] = v;
    __syncthreads();
#pragma unroll
    for (int off = 1; off < 256; off <<= 1) {
        int add = (tid >= off) ? s[tid - off] : 0;
        __syncthreads();
        s[tid] += add;
        __syncthreads();
    }
    if (tid < nb) bsum[tid] = s[tid] - v;  // exclusive
}

__global__ __launch_bounds__(256) void finalize_rowptr_kernel(const int* __restrict__ incl,
                                                              const int* __restrict__ boff,
                                                              int* __restrict__ row_ptr, int n) {
    int i = blockIdx.x * 256 + threadIdx.x;
    if (i < n) row_ptr[i + 1] = incl[i] + boff[i >> 8];
    if (i == 0) row_ptr[0] = 0;
}

__global__ __launch_bounds__(256) void fill_kernel(const int* __restrict__ src,
                                                   const int* __restrict__ dst,
                                                   const int* __restrict__ row_ptr,
                                                   int* __restrict__ cur,
                                                   int* __restrict__ srcs_sorted) {
    int e = blockIdx.x * 256 + threadIdx.x;
    if (e < NE) {
        int d = dst[e];
        int pos = row_ptr[d] + atomicAdd(&cur[d], 1);
        srcs_sorted[pos] = src[e];
    }
}

// ---------------- aggregation: one wave per dst node ----------------
__global__ __launch_bounds__(256) void aggregate_kernel(const ushort_t* __restrict__ zb,
                                                        const float* __restrict__ el,
                                                        const float* __restrict__ er,
                                                        const int* __restrict__ row_ptr,
                                                        const int* __restrict__ srcs,
                                                        const float* __restrict__ bias,
                                                        float* __restrict__ y) {
    int node = blockIdx.x * 4 + (threadIdx.x >> 6);
    int lane = threadIdx.x & 63;
    if (node >= NN) return;
    int s0 = row_ptr[node], s1 = row_ptr[node + 1];
    size_t o = (size_t)node * HD;
    if (s1 <= s0) {
        y[o + lane] = bias[lane];
        y[o + 64 + lane] = bias[64 + lane];
        y[o + 128 + lane] = bias[128 + lane];
        return;
    }
    float er0 = er[node * 3 + 0], er1 = er[node * 3 + 1], er2 = er[node * 3 + 2];

    float m0 = -1e30f, m1 = -1e30f, m2 = -1e30f;
#pragma unroll 4
    for (int i = s0; i < s1; ++i) {
        int s = srcs[i];
        float e0 = el[s * 3 + 0] + er0;
        float e1 = el[s * 3 + 1] + er1;
        float e2 = el[s * 3 + 2] + er2;
        e0 = e0 > 0.f ? e0 : 0.2f * e0;
        e1 = e1 > 0.f ? e1 : 0.2f * e1;
        e2 = e2 > 0.f ? e2 : 0.2f * e2;
        m0 = fmaxf(m0, e0);
        m1 = fmaxf(m1, e1);
        m2 = fmaxf(m2, e2);
    }
    float d0 = 0.f, d1 = 0.f, d2 = 0.f;
    float a0 = 0.f, a1 = 0.f, a2 = 0.f;
#pragma unroll 4
    for (int i = s0; i < s1; ++i) {
        int s = srcs[i];
        float e0 = el[s * 3 + 0] + er0;
        float e1 = el[s * 3 + 1] + er1;
        float e2 = el[s * 3 + 2] + er2;
        e0 = e0 > 0.f ? e0 : 0.2f * e0;
        e1 = e1 > 0.f ? e1 : 0.2f * e1;
        e2 = e2 > 0.f ? e2 : 0.2f * e2;
        float p0 = __expf(e0 - m0);
        float p1 = __expf(e1 - m1);
        float p2 = __expf(e2 - m2);
        d0 += p0; d1 += p1; d2 += p2;
        const ushort_t* zr = zb + (size_t)s * HD;
        a0 = fmaf(p0, bf2f(zr[lane]), a0);
        a1 = fmaf(p1, bf2f(zr[64 + lane]), a1);
        a2 = fmaf(p2, bf2f(zr[128 + lane]), a2);
    }
    y[o + lane] = a0 / d0 + bias[lane];
    y[o + 64 + lane] = a1 / d1 + bias[64 + lane];
    y[o + 128 + lane] = a2 / d2 + bias[128 + lane];
}

// ---------------- pooling: segmented runs (gid sorted), one wave per 16 nodes ----------------
__global__ __launch_bounds__(256) void pool_kernel(const float* __restrict__ x,
                                                   const int* __restrict__ gid,
                                                   float* __restrict__ gsum,
                                                   int* __restrict__ gcnt) {
    int w = blockIdx.x * 4 + (threadIdx.x >> 6);
    int lane = threadIdx.x & 63;
    int n0 = w * 16;
    if (n0 >= NN) return;
    int n1 = n0 + 16; if (n1 > NN) n1 = NN;
    int curg = gid[n0];
    float acc = 0.f;
    int cl = 0;
    for (int n = n0; n < n1; ++n) {
        int g = gid[n];
        if (g != curg) {
            atomicAdd(&gsum[curg * 64 + lane], acc);
            if (lane == 0) atomicAdd(&gcnt[curg], cl);
            acc = 0.f; cl = 0; curg = g;
        }
        acc += x[(size_t)n * 64 + lane];
        cl++;
    }
    atomicAdd(&gsum[curg * 64 + lane], acc);
    if (lane == 0) atomicAdd(&gcnt[curg], cl);
}

__global__ __launch_bounds__(256) void pool_final_kernel(const float* __restrict__ gsum,
                                                         const int* __restrict__ gcnt,
                                                         float* __restrict__ out) {
    int idx = blockIdx.x * 256 + threadIdx.x;
    if (idx < NG * 64) {
        int g = idx >> 6;
        float c = (float)gcnt[g];
        out[idx] = gsum[idx] / fmaxf(c, 1.0f);
    }
}

// ---------------- launch ----------------
extern "C" void kernel_launch(void* const* d_in, const int* in_sizes, int n_in,
                              void* d_out, int out_size, void* d_ws, size_t ws_size,
                              hipStream_t stream) {
    const float* feats = (const float*)d_in[0];
    const int* src = (const int*)d_in[1];
    const int* dst = (const int*)d_in[2];
    const int* gid = (const int*)d_in[3];
    const float* W1 = (const float*)d_in[4];
    const float* al1 = (const float*)d_in[5];
    const float* ar1 = (const float*)d_in[6];
    const float* b1 = (const float*)d_in[7];
    const float* W2 = (const float*)d_in[8];
    const float* al2 = (const float*)d_in[9];
    const float* ar2 = (const float*)d_in[10];
    const float* b2 = (const float*)d_in[11];
    const float* Wl = (const float*)d_in[12];
    const float* bl = (const float*)d_in[13];
    float* out = (float*)d_out;

    size_t off = 0;
    auto alloc = [&](size_t bytes) -> char* {
        char* p = (char*)d_ws + off;
        off += (bytes + 255) & ~(size_t)255;
        return p;
    };
    ushort_t* zb = (ushort_t*)alloc((size_t)NN * HD * 2);   // z in bf16
    float* y = (float*)alloc((size_t)NN * HD * 4);
    float* x = (float*)alloc((size_t)NN * 64 * 4);
    float* el = (float*)alloc((size_t)NN * 3 * 4);
    float* er = (float*)alloc((size_t)NN * 3 * 4);
    int* row_ptr = (int*)alloc((size_t)(NN + 1) * 4);
    int* cnt = (int*)alloc((size_t)NN * 4);
    int* incl = (int*)alloc((size_t)NN * 4);
    int* bsum = (int*)alloc(256 * 4);
    int* srcs = (int*)alloc((size_t)NE * 4);
    float* gsum = (float*)alloc((size_t)NG * 64 * 4);   // gcnt contiguous after
    int* gcnt = (int*)alloc((size_t)NG * 4);

    const int nbScan = (NN + 255) / 256;
    const int gridE = (NE + 255) / 256;
    const int gridNode = (NN + 3) / 4;
    const int gridGemm = (NN + 63) / 64;

    // ---- CSR build (shared by all 3 convs) ----
    hipMemsetAsync(cnt, 0, (size_t)NN * 4, stream);
    count_kernel<<<gridE, 256, 0, stream>>>(dst, cnt);
    scan_block_kernel<<<nbScan, 256, 0, stream>>>(cnt, incl, bsum, NN);
    scan_bsum_kernel<<<1, 256, 0, stream>>>(bsum, nbScan);
    finalize_rowptr_kernel<<<nbScan, 256, 0, stream>>>(incl, bsum, row_ptr, NN);
    hipMemsetAsync(cnt, 0, (size_t)NN * 4, stream);
    fill_kernel<<<gridE, 256, 0, stream>>>(src, dst, row_ptr, cnt, srcs);

    // ---- conv1 ----
    gemm_kernel<FIN, HD, true><<<gridGemm, 256, 0, stream>>>(feats, W1, nullptr, al1, ar1, el, er, nullptr, zb, NN);
    aggregate_kernel<<<gridNode, 256, 0, stream>>>(zb, el, er, row_ptr, srcs, b1, y);
    gemm_kernel<HD, 64, false><<<gridGemm, 256, 0, stream>>>(y, Wl, bl, nullptr, nullptr, nullptr, nullptr, x, nullptr, NN);

    // ---- conv2, conv3 ----
    for (int it = 0; it < 2; ++it) {
        gemm_kernel<64, HD, true><<<gridGemm, 256, 0, stream>>>(x, W2, nullptr, al2, ar2, el, er, nullptr, zb, NN);
        aggregate_kernel<<<gridNode, 256, 0, stream>>>(zb, el, er, row_ptr, srcs, b2, y);
        gemm_kernel<HD, 64, false><<<gridGemm, 256, 0, stream>>>(y, Wl, bl, nullptr, nullptr, nullptr, nullptr, x, nullptr, NN);
    }

    // ---- avg pooling ----
    hipMemsetAsync(gsum, 0, (size_t)NG * 64 * 4 + (size_t)NG * 4, stream);
    pool_kernel<<<(NN / 16 + 3) / 4 + 1, 256, 0, stream>>>(x, gid, gsum, gcnt);
    pool_final_kernel<<<(NG * 64 + 255) / 256, 256, 0, stream>>>(gsum, gcnt, out);
}

// Round 4
// 713.620 us; speedup vs baseline: 1.5011x; 1.0938x over previous
//
#include <hip/hip_runtime.h>
#include <hip/hip_bf16.h>

#define NN 50000
#define NE 800000
#define FIN 128
#define DD 64
#define NHEADS 3
#define NG 1024
#define HD 192

typedef unsigned short ushort_t;

__device__ __forceinline__ float bf2f(ushort_t u) {
    union { unsigned int i; float f; } c;
    c.i = ((unsigned int)u) << 16;
    return c.f;
}
__device__ __forceinline__ ushort_t f2bf(float f) {
    __hip_bfloat16 h = __float2bfloat16(f);
    return *reinterpret_cast<ushort_t*>(&h);
}

// ---------------- GEMM: C[nrows,M] = A[nrows,K] @ B[K,M] ----------------
// block = 256 threads, 64 rows per block; wave w -> rows w*16..+15, lane -> col h*64+lane.
// ATTN: also compute el/er (wave reduction vs al/ar), stored as float4/node; z out as bf16.
// !ATTN: add bias, output f32.
template<int K, int M, bool ATTN>
__global__ __launch_bounds__(256) void gemm_kernel(const float* __restrict__ A,
                                                   const float* __restrict__ B,
                                                   const float* __restrict__ bias,
                                                   const float* __restrict__ al,
                                                   const float* __restrict__ ar,
                                                   float* __restrict__ el4,
                                                   float* __restrict__ er4,
                                                   float* __restrict__ Cf,
                                                   ushort_t* __restrict__ Cb,
                                                   int nrows) {
    constexpr int NH = M / 64;
    __shared__ float As[64 * K];
    const int tid = threadIdx.x;
    const int row0 = blockIdx.x * 64;

    for (int idx = tid; idx < 64 * (K / 4); idx += 256) {
        int r = idx / (K / 4);
        int k4 = idx - r * (K / 4);
        float4 v = make_float4(0.f, 0.f, 0.f, 0.f);
        if (row0 + r < nrows) v = *(const float4*)(A + (size_t)(row0 + r) * K + k4 * 4);
        *(float4*)(&As[r * K + k4 * 4]) = v;
    }
    __syncthreads();

    const int lane = tid & 63;
    const int wid = tid >> 6;

    float acc[16][NH];
#pragma unroll
    for (int i = 0; i < 16; ++i)
#pragma unroll
        for (int h = 0; h < NH; ++h) acc[i][h] = 0.f;

    for (int k0 = 0; k0 < K; k0 += 4) {
        float bv[4][NH];
#pragma unroll
        for (int j = 0; j < 4; ++j)
#pragma unroll
            for (int h = 0; h < NH; ++h)
                bv[j][h] = B[(k0 + j) * M + h * 64 + lane];
#pragma unroll
        for (int i = 0; i < 16; ++i) {
            float4 a = *(const float4*)(&As[(wid * 16 + i) * K + k0]);
#pragma unroll
            for (int h = 0; h < NH; ++h) {
                acc[i][h] = fmaf(a.x, bv[0][h], acc[i][h]);
                acc[i][h] = fmaf(a.y, bv[1][h], acc[i][h]);
                acc[i][h] = fmaf(a.z, bv[2][h], acc[i][h]);
                acc[i][h] = fmaf(a.w, bv[3][h], acc[i][h]);
            }
        }
    }

    if (ATTN) {
        float alv[NH], arv[NH];
#pragma unroll
        for (int h = 0; h < NH; ++h) {
            alv[h] = al[h * 64 + lane];
            arv[h] = ar[h * 64 + lane];
        }
#pragma unroll
        for (int i = 0; i < 16; ++i) {
            int r = row0 + wid * 16 + i;
            bool valid = (r < nrows);
            float plv[NH], prv[NH];
#pragma unroll
            for (int h = 0; h < NH; ++h) {
                float pl = acc[i][h] * alv[h];
                float pr = acc[i][h] * arv[h];
#pragma unroll
                for (int off = 32; off > 0; off >>= 1) {
                    pl += __shfl_xor(pl, off);
                    pr += __shfl_xor(pr, off);
                }
                plv[h] = pl;
                prv[h] = pr;
                if (valid) Cb[(size_t)r * M + h * 64 + lane] = f2bf(acc[i][h]);
            }
            if (valid && lane == 0) {
                *(float4*)(el4 + (size_t)r * 4) = make_float4(plv[0], plv[1], plv[2], 0.f);
                *(float4*)(er4 + (size_t)r * 4) = make_float4(prv[0], prv[1], prv[2], 0.f);
            }
        }
    } else {
#pragma unroll
        for (int i = 0; i < 16; ++i) {
            int r = row0 + wid * 16 + i;
            if (r < nrows) {
#pragma unroll
                for (int h = 0; h < NH; ++h)
                    Cf[(size_t)r * M + h * 64 + lane] = acc[i][h] + bias[h * 64 + lane];
            }
        }
    }
}

// ---------------- CSR build ----------------
__global__ __launch_bounds__(256) void count_kernel(const int* __restrict__ dst, int* __restrict__ cnt) {
    int e = blockIdx.x * 256 + threadIdx.x;
    if (e < NE) atomicAdd(&cnt[dst[e]], 1);
}

__global__ __launch_bounds__(256) void scan_block_kernel(const int* __restrict__ cnt,
                                                         int* __restrict__ incl,
                                                         int* __restrict__ bsum, int n) {
    __shared__ int s[256];
    int tid = threadIdx.x;
    int i = blockIdx.x * 256 + tid;
    int v = (i < n) ? cnt[i] : 0;
    s[tid] = v;
    __syncthreads();
#pragma unroll
    for (int off = 1; off < 256; off <<= 1) {
        int add = (tid >= off) ? s[tid - off] : 0;
        __syncthreads();
        s[tid] += add;
        __syncthreads();
    }
    if (i < n) incl[i] = s[tid];
    if (tid == 255) bsum[blockIdx.x] = s[255];
}

__global__ __launch_bounds__(256) void scan_bsum_kernel(int* __restrict__ bsum, int nb) {
    __shared__ int s[256];
    int tid = threadIdx.x;
    int v = (tid < nb) ? bsum[tid] : 0;
    s[tid] = v;
    __syncthreads();
#pragma unroll
    for (int off = 1; off < 256; off <<= 1) {
        int add = (tid >= off) ? s[tid - off] : 0;
        __syncthreads();
        s[tid] += add;
        __syncthreads();
    }
    if (tid < nb) bsum[tid] = s[tid] - v;  // exclusive
}

__global__ __launch_bounds__(256) void finalize_rowptr_kernel(const int* __restrict__ incl,
                                                              const int* __restrict__ boff,
                                                              int* __restrict__ row_ptr, int n) {
    int i = blockIdx.x * 256 + threadIdx.x;
    if (i < n) row_ptr[i + 1] = incl[i] + boff[i >> 8];
    if (i == 0) row_ptr[0] = 0;
}

__global__ __launch_bounds__(256) void fill_kernel(const int* __restrict__ src,
                                                   const int* __restrict__ dst,
                                                   const int* __restrict__ row_ptr,
                                                   int* __restrict__ cur,
                                                   int* __restrict__ srcs_sorted) {
    int e = blockIdx.x * 256 + threadIdx.x;
    if (e < NE) {
        int d = dst[e];
        int pos = row_ptr[d] + atomicAdd(&cur[d], 1);
        srcs_sorted[pos] = src[e];
    }
}

// ---------------- aggregation: one wave per dst node ----------------
// Pass 1: lanes parallel over edges -> butterfly max per head.
// Pass 2: chunks of 64 edges; lane i computes p_i = exp(e_i - m) (denominator
// accumulated lane-locally), inner loop broadcasts p_j/src_j via shfl and all
// lanes do feature FMAs. NO __syncthreads (divergent per-wave loops).
__global__ __launch_bounds__(256) void aggregate_kernel(const ushort_t* __restrict__ zb,
                                                        const float* __restrict__ el4,
                                                        const float* __restrict__ er4,
                                                        const int* __restrict__ row_ptr,
                                                        const int* __restrict__ srcs,
                                                        const float* __restrict__ bias,
                                                        float* __restrict__ y) {
    int node = blockIdx.x * 4 + (threadIdx.x >> 6);
    int lane = threadIdx.x & 63;
    if (node >= NN) return;
    int s0 = row_ptr[node], s1 = row_ptr[node + 1];
    size_t o = (size_t)node * HD;

    float4 erv = *(const float4*)(er4 + (size_t)node * 4);

    // pass 1: lane-parallel max
    float m0 = -1e30f, m1 = -1e30f, m2 = -1e30f;
    for (int i = s0 + lane; i < s1; i += 64) {
        int s = srcs[i];
        float4 elv = *(const float4*)(el4 + (size_t)s * 4);
        float e0 = elv.x + erv.x, e1 = elv.y + erv.y, e2 = elv.z + erv.z;
        e0 = e0 > 0.f ? e0 : 0.2f * e0;
        e1 = e1 > 0.f ? e1 : 0.2f * e1;
        e2 = e2 > 0.f ? e2 : 0.2f * e2;
        m0 = fmaxf(m0, e0);
        m1 = fmaxf(m1, e1);
        m2 = fmaxf(m2, e2);
    }
#pragma unroll
    for (int off = 32; off > 0; off >>= 1) {
        m0 = fmaxf(m0, __shfl_xor(m0, off));
        m1 = fmaxf(m1, __shfl_xor(m1, off));
        m2 = fmaxf(m2, __shfl_xor(m2, off));
    }

    // pass 2: chunked exp + feature accumulation
    float d0 = 0.f, d1 = 0.f, d2 = 0.f;
    float a0 = 0.f, a1 = 0.f, a2 = 0.f;
    for (int c0 = s0; c0 < s1; c0 += 64) {
        int i = c0 + lane;
        float p0 = 0.f, p1 = 0.f, p2 = 0.f;
        int s = 0;
        if (i < s1) {
            s = srcs[i];
            float4 elv = *(const float4*)(el4 + (size_t)s * 4);
            float e0 = elv.x + erv.x, e1 = elv.y + erv.y, e2 = elv.z + erv.z;
            e0 = e0 > 0.f ? e0 : 0.2f * e0;
            e1 = e1 > 0.f ? e1 : 0.2f * e1;
            e2 = e2 > 0.f ? e2 : 0.2f * e2;
            p0 = __expf(e0 - m0);
            p1 = __expf(e1 - m1);
            p2 = __expf(e2 - m2);
        }
        d0 += p0; d1 += p1; d2 += p2;
        int nch = s1 - c0; if (nch > 64) nch = 64;
#pragma unroll 4
        for (int j = 0; j < nch; ++j) {
            float q0 = __shfl(p0, j);
            float q1 = __shfl(p1, j);
            float q2 = __shfl(p2, j);
            int sj = __shfl(s, j);
            const ushort_t* zr = zb + (size_t)sj * HD;
            a0 = fmaf(q0, bf2f(zr[lane]), a0);
            a1 = fmaf(q1, bf2f(zr[64 + lane]), a1);
            a2 = fmaf(q2, bf2f(zr[128 + lane]), a2);
        }
    }
#pragma unroll
    for (int off = 32; off > 0; off >>= 1) {
        d0 += __shfl_xor(d0, off);
        d1 += __shfl_xor(d1, off);
        d2 += __shfl_xor(d2, off);
    }

    y[o + lane] = a0 / d0 + bias[lane];
    y[o + 64 + lane] = a1 / d1 + bias[64 + lane];
    y[o + 128 + lane] = a2 / d2 + bias[128 + lane];
}

// ---------------- pooling: segmented runs (gid sorted), one wave per 16 nodes ----------------
__global__ __launch_bounds__(256) void pool_kernel(const float* __restrict__ x,
                                                   const int* __restrict__ gid,
                                                   float* __restrict__ gsum,
                                                   int* __restrict__ gcnt) {
    int w = blockIdx.x * 4 + (threadIdx.x >> 6);
    int lane = threadIdx.x & 63;
    int n0 = w * 16;
    if (n0 >= NN) return;
    int n1 = n0 + 16; if (n1 > NN) n1 = NN;
    int curg = gid[n0];
    float acc = 0.f;
    int cl = 0;
    for (int n = n0; n < n1; ++n) {
        int g = gid[n];
        if (g != curg) {
            atomicAdd(&gsum[curg * 64 + lane], acc);
            if (lane == 0) atomicAdd(&gcnt[curg], cl);
            acc = 0.f; cl = 0; curg = g;
        }
        acc += x[(size_t)n * 64 + lane];
        cl++;
    }
    atomicAdd(&gsum[curg * 64 + lane], acc);
    if (lane == 0) atomicAdd(&gcnt[curg], cl);
}

__global__ __launch_bounds__(256) void pool_final_kernel(const float* __restrict__ gsum,
                                                         const int* __restrict__ gcnt,
                                                         float* __restrict__ out) {
    int idx = blockIdx.x * 256 + threadIdx.x;
    if (idx < NG * 64) {
        int g = idx >> 6;
        float c = (float)gcnt[g];
        out[idx] = gsum[idx] / fmaxf(c, 1.0f);
    }
}

// ---------------- launch ----------------
extern "C" void kernel_launch(void* const* d_in, const int* in_sizes, int n_in,
                              void* d_out, int out_size, void* d_ws, size_t ws_size,
                              hipStream_t stream) {
    const float* feats = (const float*)d_in[0];
    const int* src = (const int*)d_in[1];
    const int* dst = (const int*)d_in[2];
    const int* gid = (const int*)d_in[3];
    const float* W1 = (const float*)d_in[4];
    const float* al1 = (const float*)d_in[5];
    const float* ar1 = (const float*)d_in[6];
    const float* b1 = (const float*)d_in[7];
    const float* W2 = (const float*)d_in[8];
    const float* al2 = (const float*)d_in[9];
    const float* ar2 = (const float*)d_in[10];
    const float* b2 = (const float*)d_in[11];
    const float* Wl = (const float*)d_in[12];
    const float* bl = (const float*)d_in[13];
    float* out = (float*)d_out;

    size_t off = 0;
    auto alloc = [&](size_t bytes) -> char* {
        char* p = (char*)d_ws + off;
        off += (bytes + 255) & ~(size_t)255;
        return p;
    };
    ushort_t* zb = (ushort_t*)alloc((size_t)NN * HD * 2);   // z in bf16
    float* y = (float*)alloc((size_t)NN * HD * 4);
    float* x = (float*)alloc((size_t)NN * 64 * 4);
    float* el4 = (float*)alloc((size_t)NN * 4 * 4);
    float* er4 = (float*)alloc((size_t)NN * 4 * 4);
    int* row_ptr = (int*)alloc((size_t)(NN + 1) * 4);
    int* cnt = (int*)alloc((size_t)NN * 4);
    int* incl = (int*)alloc((size_t)NN * 4);
    int* bsum = (int*)alloc(256 * 4);
    int* srcs = (int*)alloc((size_t)NE * 4);
    float* gsum = (float*)alloc((size_t)NG * 64 * 4);   // gcnt contiguous after
    int* gcnt = (int*)alloc((size_t)NG * 4);

    const int nbScan = (NN + 255) / 256;
    const int gridE = (NE + 255) / 256;
    const int gridNode = (NN + 3) / 4;
    const int gridGemm = (NN + 63) / 64;

    // ---- CSR build (shared by all 3 convs) ----
    hipMemsetAsync(cnt, 0, (size_t)NN * 4, stream);
    count_kernel<<<gridE, 256, 0, stream>>>(dst, cnt);
    scan_block_kernel<<<nbScan, 256, 0, stream>>>(cnt, incl, bsum, NN);
    scan_bsum_kernel<<<1, 256, 0, stream>>>(bsum, nbScan);
    finalize_rowptr_kernel<<<nbScan, 256, 0, stream>>>(incl, bsum, row_ptr, NN);
    hipMemsetAsync(cnt, 0, (size_t)NN * 4, stream);
    fill_kernel<<<gridE, 256, 0, stream>>>(src, dst, row_ptr, cnt, srcs);

    // ---- conv1 ----
    gemm_kernel<FIN, HD, true><<<gridGemm, 256, 0, stream>>>(feats, W1, nullptr, al1, ar1, el4, er4, nullptr, zb, NN);
    aggregate_kernel<<<gridNode, 256, 0, stream>>>(zb, el4, er4, row_ptr, srcs, b1, y);
    gemm_kernel<HD, 64, false><<<gridGemm, 256, 0, stream>>>(y, Wl, bl, nullptr, nullptr, nullptr, nullptr, x, nullptr, NN);

    // ---- conv2, conv3 ----
    for (int it = 0; it < 2; ++it) {
        gemm_kernel<64, HD, true><<<gridGemm, 256, 0, stream>>>(x, W2, nullptr, al2, ar2, el4, er4, nullptr, zb, NN);
        aggregate_kernel<<<gridNode, 256, 0, stream>>>(zb, el4, er4, row_ptr, srcs, b2, y);
        gemm_kernel<HD, 64, false><<<gridGemm, 256, 0, stream>>>(y, Wl, bl, nullptr, nullptr, nullptr, nullptr, x, nullptr, NN);
    }

    // ---- avg pooling ----
    hipMemsetAsync(gsum, 0, (size_t)NG * 64 * 4 + (size_t)NG * 4, stream);
    pool_kernel<<<(NN / 16 + 3) / 4 + 1, 256, 0, stream>>>(x, gid, gsum, gcnt);
    pool_final_kernel<<<(NG * 64 + 255) / 256, 256, 0, stream>>>(gsum, gcnt, out);
}

// Round 6
// 543.201 us; speedup vs baseline: 1.9720x; 1.3137x over previous
//
#include <hip/hip_runtime.h>
#include <hip/hip_bf16.h>

#define NN 50000
#define NE 800000
#define FIN 128
#define NHEADS 3
#define NG 1024
#define HD 192

typedef unsigned short ushort_t;
typedef __bf16 bf16x8 __attribute__((ext_vector_type(8)));
typedef float f32x4 __attribute__((ext_vector_type(4)));

__device__ __forceinline__ float bf2f(ushort_t u) {
    union { unsigned int i; float f; } c;
    c.i = ((unsigned int)u) << 16;
    return c.f;
}
__device__ __forceinline__ ushort_t f2bf(float f) {
    __hip_bfloat16 h = __float2bfloat16(f);
    return *reinterpret_cast<ushort_t*>(&h);
}

// ---------------- feats f32 -> bf16 (vectorized x4) ----------------
__global__ __launch_bounds__(256) void fconv_kernel(const float* __restrict__ f,
                                                    ushort_t* __restrict__ fb, int n4) {
    int i = blockIdx.x * 256 + threadIdx.x;
    if (i < n4) {
        float4 v = ((const float4*)f)[i];
        ushort4 o;
        o.x = f2bf(v.x); o.y = f2bf(v.y); o.z = f2bf(v.z); o.w = f2bf(v.w);
        ((ushort4*)fb)[i] = o;
    }
}

// ---------------- weight W[K][N] f32 -> Wt[N][K] bf16 ----------------
__global__ __launch_bounds__(256) void wconv_kernel(const float* __restrict__ W,
                                                    ushort_t* __restrict__ Wt, int K, int N) {
    int idx = blockIdx.x * 256 + threadIdx.x;
    if (idx < K * N) {
        int k = idx / N, n = idx - k * N;
        Wt[n * K + k] = f2bf(W[idx]);
    }
}

// ---------------- MFMA GEMM: C[nrows,NT*16] = Ab[nrows,K] @ Wt^T ----------------
// 256 thr = 4 waves, 64 rows/block, wave -> 16 rows x N cols. Register-only, no LDS.
// A frag: row = lane&15, k = (lane>>4)*8+j (contiguous 16B). B frag from Wt[N][K]:
// col row n*16+(lane&15), same k slice (contiguous 16B). C/D: col=lane&15,
// row=(lane>>4)*4+reg (verified m89 mapping).
// ATTN=1: write zb bf16 + el4/er4 (per-head reduce vs al/ar). ATTN=0: xf=acc+bias (f32) and xb bf16.
template<int K, int NT, int ATTN>
__global__ __launch_bounds__(256) void mgemm_kernel(const ushort_t* __restrict__ Ab,
                                                    const ushort_t* __restrict__ Wt,
                                                    const float* __restrict__ bias,
                                                    const float* __restrict__ al,
                                                    const float* __restrict__ ar,
                                                    float* __restrict__ el4,
                                                    float* __restrict__ er4,
                                                    float* __restrict__ xf,
                                                    ushort_t* __restrict__ xb,
                                                    ushort_t* __restrict__ zb,
                                                    int nrows) {
    constexpr int N = NT * 16;
    const int lane = threadIdx.x & 63;
    const int wid = threadIdx.x >> 6;
    const int row0 = blockIdx.x * 64 + wid * 16;
    const int m = lane & 15;
    const int kg = lane >> 4;

    int rA = row0 + m;
    if (rA > nrows - 1) rA = nrows - 1;
    const ushort_t* arow = Ab + (size_t)rA * K + kg * 8;

    const f32x4 zero4 = {0.f, 0.f, 0.f, 0.f};
    f32x4 acc[NT];
#pragma unroll
    for (int n = 0; n < NT; ++n) acc[n] = zero4;

#pragma unroll
    for (int k0 = 0; k0 < K; k0 += 32) {
        bf16x8 a = *(const bf16x8*)(arow + k0);
#pragma unroll
        for (int n = 0; n < NT; ++n) {
            bf16x8 b = *(const bf16x8*)(Wt + (size_t)(n * 16 + m) * K + k0 + kg * 8);
            acc[n] = __builtin_amdgcn_mfma_f32_16x16x32_bf16(a, b, acc[n], 0, 0, 0);
        }
    }

    const int orow = row0 + kg * 4;

    if (ATTN) {
        float sl[NHEADS][4], sr[NHEADS][4];
#pragma unroll
        for (int h = 0; h < NHEADS; ++h)
#pragma unroll
            for (int r = 0; r < 4; ++r) { sl[h][r] = 0.f; sr[h][r] = 0.f; }
#pragma unroll
        for (int n = 0; n < NT; ++n) {
            float alv = al[n * 16 + m];
            float arv = ar[n * 16 + m];
            const int h = n >> 2;
#pragma unroll
            for (int r = 0; r < 4; ++r) {
                sl[h][r] = fmaf(acc[n][r], alv, sl[h][r]);
                sr[h][r] = fmaf(acc[n][r], arv, sr[h][r]);
            }
        }
#pragma unroll
        for (int off = 1; off < 16; off <<= 1) {
#pragma unroll
            for (int h = 0; h < NHEADS; ++h)
#pragma unroll
                for (int r = 0; r < 4; ++r) {
                    sl[h][r] += __shfl_xor(sl[h][r], off);
                    sr[h][r] += __shfl_xor(sr[h][r], off);
                }
        }
#pragma unroll
        for (int r = 0; r < 4; ++r) {
            int gr = orow + r;
            if (gr < nrows) {
#pragma unroll
                for (int n = 0; n < NT; ++n)
                    zb[(size_t)gr * N + n * 16 + m] = f2bf(acc[n][r]);
                if (m == 0) {
                    *(float4*)(el4 + (size_t)gr * 4) = make_float4(sl[0][r], sl[1][r], sl[2][r], 0.f);
                    *(float4*)(er4 + (size_t)gr * 4) = make_float4(sr[0][r], sr[1][r], sr[2][r], 0.f);
                }
            }
        }
    } else {
#pragma unroll
        for (int r = 0; r < 4; ++r) {
            int gr = orow + r;
            if (gr < nrows) {
#pragma unroll
                for (int n = 0; n < NT; ++n) {
                    float v = acc[n][r] + bias[n * 16 + m];
                    xf[(size_t)gr * N + n * 16 + m] = v;
                    xb[(size_t)gr * N + n * 16 + m] = f2bf(v);
                }
            }
        }
    }
}

// ---------------- CSR build ----------------
__global__ __launch_bounds__(256) void count_kernel(const int* __restrict__ dst, int* __restrict__ cnt) {
    int e = blockIdx.x * 256 + threadIdx.x;
    if (e < NE) atomicAdd(&cnt[dst[e]], 1);
}

__global__ __launch_bounds__(256) void scan_block_kernel(const int* __restrict__ cnt,
                                                         int* __restrict__ incl,
                                                         int* __restrict__ bsum, int n) {
    __shared__ int s[256];
    int tid = threadIdx.x;
    int i = blockIdx.x * 256 + tid;
    int v = (i < n) ? cnt[i] : 0;
    s[tid] = v;
    __syncthreads();
#pragma unroll
    for (int off = 1; off < 256; off <<= 1) {
        int add = (tid >= off) ? s[tid - off] : 0;
        __syncthreads();
        s[tid] += add;
        __syncthreads();
    }
    if (i < n) incl[i] = s[tid];
    if (tid == 255) bsum[blockIdx.x] = s[255];
}

__global__ __launch_bounds__(256) void scan_bsum_kernel(int* __restrict__ bsum, int nb) {
    __shared__ int s[256];
    int tid = threadIdx.x;
    int v = (tid < nb) ? bsum[tid] : 0;
    s[tid] = v;
    __syncthreads();
#pragma unroll
    for (int off = 1; off < 256; off <<= 1) {
        int add = (tid >= off) ? s[tid - off] : 0;
        __syncthreads();
        s[tid] += add;
        __syncthreads();
    }
    if (tid < nb) bsum[tid] = s[tid] - v;  // exclusive
}

__global__ __launch_bounds__(256) void finalize_rowptr_kernel(const int* __restrict__ incl,
                                                              const int* __restrict__ boff,
                                                              int* __restrict__ row_ptr, int n) {
    int i = blockIdx.x * 256 + threadIdx.x;
    if (i < n) row_ptr[i + 1] = incl[i] + boff[i >> 8];
    if (i == 0) row_ptr[0] = 0;
}

__global__ __launch_bounds__(256) void fill_kernel(const int* __restrict__ src,
                                                   const int* __restrict__ dst,
                                                   const int* __restrict__ row_ptr,
                                                   int* __restrict__ cur,
                                                   int* __restrict__ srcs_sorted) {
    int e = blockIdx.x * 256 + threadIdx.x;
    if (e < NE) {
        int d = dst[e];
        int pos = row_ptr[d] + atomicAdd(&cur[d], 1);
        srcs_sorted[pos] = src[e];
    }
}

// ---------------- aggregation: one wave per dst node ----------------
__global__ __launch_bounds__(256) void aggregate_kernel(const ushort_t* __restrict__ zb,
                                                        const float* __restrict__ el4,
                                                        const float* __restrict__ er4,
                                                        const int* __restrict__ row_ptr,
                                                        const int* __restrict__ srcs,
                                                        const float* __restrict__ bias,
                                                        ushort_t* __restrict__ yb) {
    int node = blockIdx.x * 4 + (threadIdx.x >> 6);
    int lane = threadIdx.x & 63;
    if (node >= NN) return;
    int s0 = row_ptr[node], s1 = row_ptr[node + 1];
    size_t o = (size_t)node * HD;

    float4 erv = *(const float4*)(er4 + (size_t)node * 4);

    // pass 1: lane-parallel max
    float m0 = -1e30f, m1 = -1e30f, m2 = -1e30f;
    for (int i = s0 + lane; i < s1; i += 64) {
        int s = srcs[i];
        float4 elv = *(const float4*)(el4 + (size_t)s * 4);
        float e0 = elv.x + erv.x, e1 = elv.y + erv.y, e2 = elv.z + erv.z;
        e0 = e0 > 0.f ? e0 : 0.2f * e0;
        e1 = e1 > 0.f ? e1 : 0.2f * e1;
        e2 = e2 > 0.f ? e2 : 0.2f * e2;
        m0 = fmaxf(m0, e0);
        m1 = fmaxf(m1, e1);
        m2 = fmaxf(m2, e2);
    }
#pragma unroll
    for (int off = 32; off > 0; off >>= 1) {
        m0 = fmaxf(m0, __shfl_xor(m0, off));
        m1 = fmaxf(m1, __shfl_xor(m1, off));
        m2 = fmaxf(m2, __shfl_xor(m2, off));
    }

    // pass 2: chunked exp + feature accumulation
    float d0 = 0.f, d1 = 0.f, d2 = 0.f;
    float a0 = 0.f, a1 = 0.f, a2 = 0.f;
    for (int c0 = s0; c0 < s1; c0 += 64) {
        int i = c0 + lane;
        float p0 = 0.f, p1 = 0.f, p2 = 0.f;
        int s = 0;
        if (i < s1) {
            s = srcs[i];
            float4 elv = *(const float4*)(el4 + (size_t)s * 4);
            float e0 = elv.x + erv.x, e1 = elv.y + erv.y, e2 = elv.z + erv.z;
            e0 = e0 > 0.f ? e0 : 0.2f * e0;
            e1 = e1 > 0.f ? e1 : 0.2f * e1;
            e2 = e2 > 0.f ? e2 : 0.2f * e2;
            p0 = __expf(e0 - m0);
            p1 = __expf(e1 - m1);
            p2 = __expf(e2 - m2);
        }
        d0 += p0; d1 += p1; d2 += p2;
        int nch = s1 - c0; if (nch > 64) nch = 64;
#pragma unroll 4
        for (int j = 0; j < nch; ++j) {
            float q0 = __shfl(p0, j);
            float q1 = __shfl(p1, j);
            float q2 = __shfl(p2, j);
            int sj = __shfl(s, j);
            const ushort_t* zr = zb + (size_t)sj * HD;
            a0 = fmaf(q0, bf2f(zr[lane]), a0);
            a1 = fmaf(q1, bf2f(zr[64 + lane]), a1);
            a2 = fmaf(q2, bf2f(zr[128 + lane]), a2);
        }
    }
#pragma unroll
    for (int off = 32; off > 0; off >>= 1) {
        d0 += __shfl_xor(d0, off);
        d1 += __shfl_xor(d1, off);
        d2 += __shfl_xor(d2, off);
    }

    yb[o + lane] = f2bf(a0 / d0 + bias[lane]);
    yb[o + 64 + lane] = f2bf(a1 / d1 + bias[64 + lane]);
    yb[o + 128 + lane] = f2bf(a2 / d2 + bias[128 + lane]);
}

// ---------------- pooling ----------------
__global__ __launch_bounds__(256) void pool_kernel(const float* __restrict__ x,
                                                   const int* __restrict__ gid,
                                                   float* __restrict__ gsum,
                                                   int* __restrict__ gcnt) {
    int w = blockIdx.x * 4 + (threadIdx.x >> 6);
    int lane = threadIdx.x & 63;
    int n0 = w * 16;
    if (n0 >= NN) return;
    int n1 = n0 + 16; if (n1 > NN) n1 = NN;
    int curg = gid[n0];
    float acc = 0.f;
    int cl = 0;
    for (int n = n0; n < n1; ++n) {
        int g = gid[n];
        if (g != curg) {
            atomicAdd(&gsum[curg * 64 + lane], acc);
            if (lane == 0) atomicAdd(&gcnt[curg], cl);
            acc = 0.f; cl = 0; curg = g;
        }
        acc += x[(size_t)n * 64 + lane];
        cl++;
    }
    atomicAdd(&gsum[curg * 64 + lane], acc);
    if (lane == 0) atomicAdd(&gcnt[curg], cl);
}

__global__ __launch_bounds__(256) void pool_final_kernel(const float* __restrict__ gsum,
                                                         const int* __restrict__ gcnt,
                                                         float* __restrict__ out) {
    int idx = blockIdx.x * 256 + threadIdx.x;
    if (idx < NG * 64) {
        int g = idx >> 6;
        float c = (float)gcnt[g];
        out[idx] = gsum[idx] / fmaxf(c, 1.0f);
    }
}

// ---------------- launch ----------------
extern "C" void kernel_launch(void* const* d_in, const int* in_sizes, int n_in,
                              void* d_out, int out_size, void* d_ws, size_t ws_size,
                              hipStream_t stream) {
    const float* feats = (const float*)d_in[0];
    const int* src = (const int*)d_in[1];
    const int* dst = (const int*)d_in[2];
    const int* gid = (const int*)d_in[3];
    const float* W1 = (const float*)d_in[4];
    const float* al1 = (const float*)d_in[5];
    const float* ar1 = (const float*)d_in[6];
    const float* b1 = (const float*)d_in[7];
    const float* W2 = (const float*)d_in[8];
    const float* al2 = (const float*)d_in[9];
    const float* ar2 = (const float*)d_in[10];
    const float* b2 = (const float*)d_in[11];
    const float* Wl = (const float*)d_in[12];
    const float* bl = (const float*)d_in[13];
    float* out = (float*)d_out;

    size_t off = 0;
    auto alloc = [&](size_t bytes) -> char* {
        char* p = (char*)d_ws + off;
        off += (bytes + 255) & ~(size_t)255;
        return p;
    };
    ushort_t* featsb = (ushort_t*)alloc((size_t)NN * FIN * 2);
    ushort_t* zb = (ushort_t*)alloc((size_t)NN * HD * 2);
    ushort_t* yb = (ushort_t*)alloc((size_t)NN * HD * 2);
    ushort_t* xb = (ushort_t*)alloc((size_t)NN * 64 * 2);
    float* xf = (float*)alloc((size_t)NN * 64 * 4);
    float* el4 = (float*)alloc((size_t)NN * 4 * 4);
    float* er4 = (float*)alloc((size_t)NN * 4 * 4);
    ushort_t* W1t = (ushort_t*)alloc((size_t)HD * FIN * 2);  // [192][128]
    ushort_t* W2t = (ushort_t*)alloc((size_t)HD * 64 * 2);   // [192][64]
    ushort_t* Wlt = (ushort_t*)alloc((size_t)64 * HD * 2);   // [64][192]
    int* row_ptr = (int*)alloc((size_t)(NN + 1) * 4);
    int* cnt = (int*)alloc((size_t)NN * 4);
    int* incl = (int*)alloc((size_t)NN * 4);
    int* bsum = (int*)alloc(256 * 4);
    int* srcs = (int*)alloc((size_t)NE * 4);
    float* gsum = (float*)alloc((size_t)NG * 64 * 4);
    int* gcnt = (int*)alloc((size_t)NG * 4);

    const int nbScan = (NN + 255) / 256;
    const int gridE = (NE + 255) / 256;
    const int gridNode = (NN + 3) / 4;
    const int gridGemm = (NN + 63) / 64;

    // ---- input conversions (bf16) ----
    fconv_kernel<<<(NN * FIN / 4 + 255) / 256, 256, 0, stream>>>(feats, featsb, NN * FIN / 4);
    wconv_kernel<<<(FIN * HD + 255) / 256, 256, 0, stream>>>(W1, W1t, FIN, HD);
    wconv_kernel<<<(64 * HD + 255) / 256, 256, 0, stream>>>(W2, W2t, 64, HD);
    wconv_kernel<<<(HD * 64 + 255) / 256, 256, 0, stream>>>(Wl, Wlt, HD, 64);

    // ---- CSR build (shared by all 3 convs) ----
    hipMemsetAsync(cnt, 0, (size_t)NN * 4, stream);
    count_kernel<<<gridE, 256, 0, stream>>>(dst, cnt);
    scan_block_kernel<<<nbScan, 256, 0, stream>>>(cnt, incl, bsum, NN);
    scan_bsum_kernel<<<1, 256, 0, stream>>>(bsum, nbScan);
    finalize_rowptr_kernel<<<nbScan, 256, 0, stream>>>(incl, bsum, row_ptr, NN);
    hipMemsetAsync(cnt, 0, (size_t)NN * 4, stream);
    fill_kernel<<<gridE, 256, 0, stream>>>(src, dst, row_ptr, cnt, srcs);

    // ---- conv1 ----
    mgemm_kernel<FIN, 12, 1><<<gridGemm, 256, 0, stream>>>(featsb, W1t, nullptr, al1, ar1,
                                                           el4, er4, nullptr, nullptr, zb, NN);
    aggregate_kernel<<<gridNode, 256, 0, stream>>>(zb, el4, er4, row_ptr, srcs, b1, yb);
    mgemm_kernel<HD, 4, 0><<<gridGemm, 256, 0, stream>>>(yb, Wlt, bl, nullptr, nullptr,
                                                         nullptr, nullptr, xf, xb, nullptr, NN);

    // ---- conv2, conv3 ----
    for (int it = 0; it < 2; ++it) {
        mgemm_kernel<64, 12, 1><<<gridGemm, 256, 0, stream>>>(xb, W2t, nullptr, al2, ar2,
                                                              el4, er4, nullptr, nullptr, zb, NN);
        aggregate_kernel<<<gridNode, 256, 0, stream>>>(zb, el4, er4, row_ptr, srcs, b2, yb);
        mgemm_kernel<HD, 4, 0><<<gridGemm, 256, 0, stream>>>(yb, Wlt, bl, nullptr, nullptr,
                                                             nullptr, nullptr, xf, xb, nullptr, NN);
    }

    // ---- avg pooling ----
    hipMemsetAsync(gsum, 0, (size_t)NG * 64 * 4 + (size_t)NG * 4, stream);
    pool_kernel<<<(NN / 16 + 3) / 4 + 1, 256, 0, stream>>>(xf, gid, gsum, gcnt);
    pool_final_kernel<<<(NG * 64 + 255) / 256, 256, 0, stream>>>(gsum, gcnt, out);
}

// Round 7
// 535.967 us; speedup vs baseline: 1.9987x; 1.0135x over previous
//
#include <hip/hip_runtime.h>
#include <hip/hip_bf16.h>

#define NN 50000
#define NE 800000
#define FIN 128
#define NHEADS 3
#define NG 1024
#define HD 192

typedef unsigned short ushort_t;
typedef __bf16 bf16x8 __attribute__((ext_vector_type(8)));
typedef float f32x4 __attribute__((ext_vector_type(4)));

__device__ __forceinline__ float bf2f(ushort_t u) {
    union { unsigned int i; float f; } c;
    c.i = ((unsigned int)u) << 16;
    return c.f;
}
__device__ __forceinline__ ushort_t f2bf(float f) {
    __hip_bfloat16 h = __float2bfloat16(f);
    return *reinterpret_cast<ushort_t*>(&h);
}
__device__ __forceinline__ float readlane_f(float v, int l) {
    return __int_as_float(__builtin_amdgcn_readlane(__float_as_int(v), l));
}

// ---------------- feats f32 -> bf16 (vectorized x4) ----------------
__global__ __launch_bounds__(256) void fconv_kernel(const float* __restrict__ f,
                                                    ushort_t* __restrict__ fb, int n4) {
    int i = blockIdx.x * 256 + threadIdx.x;
    if (i < n4) {
        float4 v = ((const float4*)f)[i];
        ushort4 o;
        o.x = f2bf(v.x); o.y = f2bf(v.y); o.z = f2bf(v.z); o.w = f2bf(v.w);
        ((ushort4*)fb)[i] = o;
    }
}

// ---------------- weight W[K][N] f32 -> Wt[N][K] bf16 ----------------
__global__ __launch_bounds__(256) void wconv_kernel(const float* __restrict__ W,
                                                    ushort_t* __restrict__ Wt, int K, int N) {
    int idx = blockIdx.x * 256 + threadIdx.x;
    if (idx < K * N) {
        int k = idx / N, n = idx - k * N;
        Wt[n * K + k] = f2bf(W[idx]);
    }
}

// ---------------- MFMA GEMM: C[nrows,NT*16] = Ab[nrows,K] @ Wt^T ----------------
// 256 thr = 4 waves, 64 rows/block, wave -> 16 rows x N cols. Register-only, no LDS.
// A frag: row = lane&15, k = (lane>>4)*8+j (contiguous 16B). B frag from Wt[N][K].
// C/D: col=lane&15, row=(lane>>4)*4+reg (verified m89 mapping).
template<int K, int NT, int ATTN>
__global__ __launch_bounds__(256) void mgemm_kernel(const ushort_t* __restrict__ Ab,
                                                    const ushort_t* __restrict__ Wt,
                                                    const float* __restrict__ bias,
                                                    const float* __restrict__ al,
                                                    const float* __restrict__ ar,
                                                    float* __restrict__ el4,
                                                    float* __restrict__ er4,
                                                    float* __restrict__ xf,
                                                    ushort_t* __restrict__ xb,
                                                    ushort_t* __restrict__ zb,
                                                    int nrows) {
    constexpr int N = NT * 16;
    const int lane = threadIdx.x & 63;
    const int wid = threadIdx.x >> 6;
    const int row0 = blockIdx.x * 64 + wid * 16;
    const int m = lane & 15;
    const int kg = lane >> 4;

    int rA = row0 + m;
    if (rA > nrows - 1) rA = nrows - 1;
    const ushort_t* arow = Ab + (size_t)rA * K + kg * 8;

    const f32x4 zero4 = {0.f, 0.f, 0.f, 0.f};
    f32x4 acc[NT];
#pragma unroll
    for (int n = 0; n < NT; ++n) acc[n] = zero4;

#pragma unroll
    for (int k0 = 0; k0 < K; k0 += 32) {
        bf16x8 a = *(const bf16x8*)(arow + k0);
#pragma unroll
        for (int n = 0; n < NT; ++n) {
            bf16x8 b = *(const bf16x8*)(Wt + (size_t)(n * 16 + m) * K + k0 + kg * 8);
            acc[n] = __builtin_amdgcn_mfma_f32_16x16x32_bf16(a, b, acc[n], 0, 0, 0);
        }
    }

    const int orow = row0 + kg * 4;

    if (ATTN) {
        float sl[NHEADS][4], sr[NHEADS][4];
#pragma unroll
        for (int h = 0; h < NHEADS; ++h)
#pragma unroll
            for (int r = 0; r < 4; ++r) { sl[h][r] = 0.f; sr[h][r] = 0.f; }
#pragma unroll
        for (int n = 0; n < NT; ++n) {
            float alv = al[n * 16 + m];
            float arv = ar[n * 16 + m];
            const int h = n >> 2;
#pragma unroll
            for (int r = 0; r < 4; ++r) {
                sl[h][r] = fmaf(acc[n][r], alv, sl[h][r]);
                sr[h][r] = fmaf(acc[n][r], arv, sr[h][r]);
            }
        }
#pragma unroll
        for (int off = 1; off < 16; off <<= 1) {
#pragma unroll
            for (int h = 0; h < NHEADS; ++h)
#pragma unroll
                for (int r = 0; r < 4; ++r) {
                    sl[h][r] += __shfl_xor(sl[h][r], off);
                    sr[h][r] += __shfl_xor(sr[h][r], off);
                }
        }
#pragma unroll
        for (int r = 0; r < 4; ++r) {
            int gr = orow + r;
            if (gr < nrows) {
#pragma unroll
                for (int n = 0; n < NT; ++n)
                    zb[(size_t)gr * N + n * 16 + m] = f2bf(acc[n][r]);
                if (m == 0) {
                    *(float4*)(el4 + (size_t)gr * 4) = make_float4(sl[0][r], sl[1][r], sl[2][r], 0.f);
                    *(float4*)(er4 + (size_t)gr * 4) = make_float4(sr[0][r], sr[1][r], sr[2][r], 0.f);
                }
            }
        }
    } else {
#pragma unroll
        for (int r = 0; r < 4; ++r) {
            int gr = orow + r;
            if (gr < nrows) {
#pragma unroll
                for (int n = 0; n < NT; ++n) {
                    float v = acc[n][r] + bias[n * 16 + m];
                    xf[(size_t)gr * N + n * 16 + m] = v;
                    xb[(size_t)gr * N + n * 16 + m] = f2bf(v);
                }
            }
        }
    }
}

// ---------------- CSR build ----------------
__global__ __launch_bounds__(256) void count_kernel(const int* __restrict__ dst, int* __restrict__ cnt) {
    int e = blockIdx.x * 256 + threadIdx.x;
    if (e < NE) atomicAdd(&cnt[dst[e]], 1);
}

__global__ __launch_bounds__(256) void scan_block_kernel(const int* __restrict__ cnt,
                                                         int* __restrict__ incl,
                                                         int* __restrict__ bsum, int n) {
    __shared__ int s[256];
    int tid = threadIdx.x;
    int i = blockIdx.x * 256 + tid;
    int v = (i < n) ? cnt[i] : 0;
    s[tid] = v;
    __syncthreads();
#pragma unroll
    for (int off = 1; off < 256; off <<= 1) {
        int add = (tid >= off) ? s[tid - off] : 0;
        __syncthreads();
        s[tid] += add;
        __syncthreads();
    }
    if (i < n) incl[i] = s[tid];
    if (tid == 255) bsum[blockIdx.x] = s[255];
}

__global__ __launch_bounds__(256) void scan_bsum_kernel(int* __restrict__ bsum, int nb) {
    __shared__ int s[256];
    int tid = threadIdx.x;
    int v = (tid < nb) ? bsum[tid] : 0;
    s[tid] = v;
    __syncthreads();
#pragma unroll
    for (int off = 1; off < 256; off <<= 1) {
        int add = (tid >= off) ? s[tid - off] : 0;
        __syncthreads();
        s[tid] += add;
        __syncthreads();
    }
    if (tid < nb) bsum[tid] = s[tid] - v;  // exclusive
}

__global__ __launch_bounds__(256) void finalize_rowptr_kernel(const int* __restrict__ incl,
                                                              const int* __restrict__ boff,
                                                              int* __restrict__ row_ptr, int n) {
    int i = blockIdx.x * 256 + threadIdx.x;
    if (i < n) row_ptr[i + 1] = incl[i] + boff[i >> 8];
    if (i == 0) row_ptr[0] = 0;
}

__global__ __launch_bounds__(256) void fill_kernel(const int* __restrict__ src,
                                                   const int* __restrict__ dst,
                                                   const int* __restrict__ row_ptr,
                                                   int* __restrict__ cur,
                                                   int* __restrict__ srcs_sorted) {
    int e = blockIdx.x * 256 + threadIdx.x;
    if (e < NE) {
        int d = dst[e];
        int pos = row_ptr[d] + atomicAdd(&cur[d], 1);
        srcs_sorted[pos] = src[e];
    }
}

// ---------------- aggregation: one wave per dst node, single pass ----------------
// No max-subtraction (softmax shift-invariant; scores ~N(0,2) << 88, clamp 60 as guard).
// Lane i computes exp-scores for edge c0+i; inner loop broadcasts (readlane) p/src and
// lanes 0..47 each load ushort4 (8B) -> one wave-instruction per 384B z row.
// Lane l owns output dims 4l..4l+3 (row-major layout preserved).
__global__ __launch_bounds__(256) void aggregate_kernel(const ushort_t* __restrict__ zb,
                                                        const float* __restrict__ el4,
                                                        const float* __restrict__ er4,
                                                        const int* __restrict__ row_ptr,
                                                        const int* __restrict__ srcs,
                                                        const float* __restrict__ bias,
                                                        ushort_t* __restrict__ yb) {
    int node = blockIdx.x * 4 + (threadIdx.x >> 6);
    int lane = threadIdx.x & 63;
    if (node >= NN) return;
    int s0 = row_ptr[node], s1 = row_ptr[node + 1];
    size_t o = (size_t)node * HD;
    const int h = lane >> 4;  // head for owned dims (lanes 0..47)

    float4 erv = *(const float4*)(er4 + (size_t)node * 4);

    float d0 = 0.f, d1 = 0.f, d2 = 0.f;
    f32x4 a = {0.f, 0.f, 0.f, 0.f};

    for (int c0 = s0; c0 < s1; c0 += 64) {
        int i = c0 + lane;
        float p0 = 0.f, p1 = 0.f, p2 = 0.f;
        int s = 0;
        if (i < s1) {
            s = srcs[i];
            float4 elv = *(const float4*)(el4 + (size_t)s * 4);
            float e0 = elv.x + erv.x, e1 = elv.y + erv.y, e2 = elv.z + erv.z;
            e0 = e0 > 0.f ? e0 : 0.2f * e0;
            e1 = e1 > 0.f ? e1 : 0.2f * e1;
            e2 = e2 > 0.f ? e2 : 0.2f * e2;
            p0 = __expf(fminf(e0, 60.f));
            p1 = __expf(fminf(e1, 60.f));
            p2 = __expf(fminf(e2, 60.f));
        }
        d0 += p0; d1 += p1; d2 += p2;
        int nch = s1 - c0; if (nch > 64) nch = 64;
        for (int j = 0; j < nch; ++j) {
            int sj = __builtin_amdgcn_readlane(s, j);
            float q0 = readlane_f(p0, j);
            float q1 = readlane_f(p1, j);
            float q2 = readlane_f(p2, j);
            float q = (h == 0) ? q0 : ((h == 1) ? q1 : q2);
            if (lane < 48) {
                ushort4 zv = *(const ushort4*)(zb + (size_t)sj * HD + lane * 4);
                a[0] = fmaf(q, bf2f(zv.x), a[0]);
                a[1] = fmaf(q, bf2f(zv.y), a[1]);
                a[2] = fmaf(q, bf2f(zv.z), a[2]);
                a[3] = fmaf(q, bf2f(zv.w), a[3]);
            }
        }
    }
#pragma unroll
    for (int off = 32; off > 0; off >>= 1) {
        d0 += __shfl_xor(d0, off);
        d1 += __shfl_xor(d1, off);
        d2 += __shfl_xor(d2, off);
    }

    if (lane < 48) {
        float dd = (h == 0) ? d0 : ((h == 1) ? d1 : d2);
        float rinv = 1.0f / dd;
        float4 bb = *(const float4*)(bias + lane * 4);
        ushort4 ov;
        ov.x = f2bf(a[0] * rinv + bb.x);
        ov.y = f2bf(a[1] * rinv + bb.y);
        ov.z = f2bf(a[2] * rinv + bb.z);
        ov.w = f2bf(a[3] * rinv + bb.w);
        *(ushort4*)(yb + o + lane * 4) = ov;
    }
}

// ---------------- pooling ----------------
__global__ __launch_bounds__(256) void pool_kernel(const float* __restrict__ x,
                                                   const int* __restrict__ gid,
                                                   float* __restrict__ gsum,
                                                   int* __restrict__ gcnt) {
    int w = blockIdx.x * 4 + (threadIdx.x >> 6);
    int lane = threadIdx.x & 63;
    int n0 = w * 16;
    if (n0 >= NN) return;
    int n1 = n0 + 16; if (n1 > NN) n1 = NN;
    int curg = gid[n0];
    float acc = 0.f;
    int cl = 0;
    for (int n = n0; n < n1; ++n) {
        int g = gid[n];
        if (g != curg) {
            atomicAdd(&gsum[curg * 64 + lane], acc);
            if (lane == 0) atomicAdd(&gcnt[curg], cl);
            acc = 0.f; cl = 0; curg = g;
        }
        acc += x[(size_t)n * 64 + lane];
        cl++;
    }
    atomicAdd(&gsum[curg * 64 + lane], acc);
    if (lane == 0) atomicAdd(&gcnt[curg], cl);
}

__global__ __launch_bounds__(256) void pool_final_kernel(const float* __restrict__ gsum,
                                                         const int* __restrict__ gcnt,
                                                         float* __restrict__ out) {
    int idx = blockIdx.x * 256 + threadIdx.x;
    if (idx < NG * 64) {
        int g = idx >> 6;
        float c = (float)gcnt[g];
        out[idx] = gsum[idx] / fmaxf(c, 1.0f);
    }
}

// ---------------- launch ----------------
extern "C" void kernel_launch(void* const* d_in, const int* in_sizes, int n_in,
                              void* d_out, int out_size, void* d_ws, size_t ws_size,
                              hipStream_t stream) {
    const float* feats = (const float*)d_in[0];
    const int* src = (const int*)d_in[1];
    const int* dst = (const int*)d_in[2];
    const int* gid = (const int*)d_in[3];
    const float* W1 = (const float*)d_in[4];
    const float* al1 = (const float*)d_in[5];
    const float* ar1 = (const float*)d_in[6];
    const float* b1 = (const float*)d_in[7];
    const float* W2 = (const float*)d_in[8];
    const float* al2 = (const float*)d_in[9];
    const float* ar2 = (const float*)d_in[10];
    const float* b2 = (const float*)d_in[11];
    const float* Wl = (const float*)d_in[12];
    const float* bl = (const float*)d_in[13];
    float* out = (float*)d_out;

    size_t off = 0;
    auto alloc = [&](size_t bytes) -> char* {
        char* p = (char*)d_ws + off;
        off += (bytes + 255) & ~(size_t)255;
        return p;
    };
    ushort_t* featsb = (ushort_t*)alloc((size_t)NN * FIN * 2);
    ushort_t* zb = (ushort_t*)alloc((size_t)NN * HD * 2);
    ushort_t* yb = (ushort_t*)alloc((size_t)NN * HD * 2);
    ushort_t* xb = (ushort_t*)alloc((size_t)NN * 64 * 2);
    float* xf = (float*)alloc((size_t)NN * 64 * 4);
    float* el4 = (float*)alloc((size_t)NN * 4 * 4);
    float* er4 = (float*)alloc((size_t)NN * 4 * 4);
    ushort_t* W1t = (ushort_t*)alloc((size_t)HD * FIN * 2);  // [192][128]
    ushort_t* W2t = (ushort_t*)alloc((size_t)HD * 64 * 2);   // [192][64]
    ushort_t* Wlt = (ushort_t*)alloc((size_t)64 * HD * 2);   // [64][192]
    int* row_ptr = (int*)alloc((size_t)(NN + 1) * 4);
    int* cnt = (int*)alloc((size_t)NN * 4);
    int* incl = (int*)alloc((size_t)NN * 4);
    int* bsum = (int*)alloc(256 * 4);
    int* srcs = (int*)alloc((size_t)NE * 4);
    float* gsum = (float*)alloc((size_t)NG * 64 * 4);
    int* gcnt = (int*)alloc((size_t)NG * 4);

    const int nbScan = (NN + 255) / 256;
    const int gridE = (NE + 255) / 256;
    const int gridNode = (NN + 3) / 4;
    const int gridGemm = (NN + 63) / 64;

    // ---- input conversions (bf16) ----
    fconv_kernel<<<(NN * FIN / 4 + 255) / 256, 256, 0, stream>>>(feats, featsb, NN * FIN / 4);
    wconv_kernel<<<(FIN * HD + 255) / 256, 256, 0, stream>>>(W1, W1t, FIN, HD);
    wconv_kernel<<<(64 * HD + 255) / 256, 256, 0, stream>>>(W2, W2t, 64, HD);
    wconv_kernel<<<(HD * 64 + 255) / 256, 256, 0, stream>>>(Wl, Wlt, HD, 64);

    // ---- CSR build (shared by all 3 convs) ----
    hipMemsetAsync(cnt, 0, (size_t)NN * 4, stream);
    count_kernel<<<gridE, 256, 0, stream>>>(dst, cnt);
    scan_block_kernel<<<nbScan, 256, 0, stream>>>(cnt, incl, bsum, NN);
    scan_bsum_kernel<<<1, 256, 0, stream>>>(bsum, nbScan);
    finalize_rowptr_kernel<<<nbScan, 256, 0, stream>>>(incl, bsum, row_ptr, NN);
    hipMemsetAsync(cnt, 0, (size_t)NN * 4, stream);
    fill_kernel<<<gridE, 256, 0, stream>>>(src, dst, row_ptr, cnt, srcs);

    // ---- conv1 ----
    mgemm_kernel<FIN, 12, 1><<<gridGemm, 256, 0, stream>>>(featsb, W1t, nullptr, al1, ar1,
                                                           el4, er4, nullptr, nullptr, zb, NN);
    aggregate_kernel<<<gridNode, 256, 0, stream>>>(zb, el4, er4, row_ptr, srcs, b1, yb);
    mgemm_kernel<HD, 4, 0><<<gridGemm, 256, 0, stream>>>(yb, Wlt, bl, nullptr, nullptr,
                                                         nullptr, nullptr, xf, xb, nullptr, NN);

    // ---- conv2, conv3 ----
    for (int it = 0; it < 2; ++it) {
        mgemm_kernel<64, 12, 1><<<gridGemm, 256, 0, stream>>>(xb, W2t, nullptr, al2, ar2,
                                                              el4, er4, nullptr, nullptr, zb, NN);
        aggregate_kernel<<<gridNode, 256, 0, stream>>>(zb, el4, er4, row_ptr, srcs, b2, yb);
        mgemm_kernel<HD, 4, 0><<<gridGemm, 256, 0, stream>>>(yb, Wlt, bl, nullptr, nullptr,
                                                             nullptr, nullptr, xf, xb, nullptr, NN);
    }

    // ---- avg pooling ----
    hipMemsetAsync(gsum, 0, (size_t)NG * 64 * 4 + (size_t)NG * 4, stream);
    pool_kernel<<<(NN / 16 + 3) / 4 + 1, 256, 0, stream>>>(xf, gid, gsum, gcnt);
    pool_final_kernel<<<(NG * 64 + 255) / 256, 256, 0, stream>>>(gsum, gcnt, out);
}

// Round 8
// 472.651 us; speedup vs baseline: 2.2664x; 1.1340x over previous
//
#include <hip/hip_runtime.h>
#include <hip/hip_bf16.h>

#define NN 50000
#define NE 800000
#define FIN 128
#define NHEADS 3
#define NG 1024
#define HD 192

typedef unsigned short ushort_t;
typedef __bf16 bf16x8 __attribute__((ext_vector_type(8)));
typedef float f32x4 __attribute__((ext_vector_type(4)));

__device__ __forceinline__ float bf2f(ushort_t u) {
    union { unsigned int i; float f; } c;
    c.i = ((unsigned int)u) << 16;
    return c.f;
}
__device__ __forceinline__ ushort_t f2bf(float f) {
    __hip_bfloat16 h = __float2bfloat16(f);
    return *reinterpret_cast<ushort_t*>(&h);
}
__device__ __forceinline__ float readlane_f(float v, int l) {
    return __int_as_float(__builtin_amdgcn_readlane(__float_as_int(v), l));
}

// ---------------- feats f32 -> bf16 (vectorized x4) ----------------
__global__ __launch_bounds__(256) void fconv_kernel(const float* __restrict__ f,
                                                    ushort_t* __restrict__ fb, int n4) {
    int i = blockIdx.x * 256 + threadIdx.x;
    if (i < n4) {
        float4 v = ((const float4*)f)[i];
        ushort4 o;
        o.x = f2bf(v.x); o.y = f2bf(v.y); o.z = f2bf(v.z); o.w = f2bf(v.w);
        ((ushort4*)fb)[i] = o;
    }
}

// ---------------- weight W[K][N] f32 -> Wt[N][K] bf16 ----------------
__global__ __launch_bounds__(256) void wconv_kernel(const float* __restrict__ W,
                                                    ushort_t* __restrict__ Wt, int K, int N) {
    int idx = blockIdx.x * 256 + threadIdx.x;
    if (idx < K * N) {
        int k = idx / N, n = idx - k * N;
        Wt[n * K + k] = f2bf(W[idx]);
    }
}

// ---------------- MFMA GEMM: C[nrows,NT*16] = Ab[nrows,K] @ Wt^T ----------------
// 256 thr = 4 waves, 64 rows/block, wave -> 16 rows x N cols. Register-only, no LDS.
// A frag: row = lane&15, k = (lane>>4)*8+j (contiguous 16B). B frag from Wt[N][K].
// C/D: col=lane&15, row=(lane>>4)*4+reg (verified m89 mapping).
template<int K, int NT, int ATTN>
__global__ __launch_bounds__(256) void mgemm_kernel(const ushort_t* __restrict__ Ab,
                                                    const ushort_t* __restrict__ Wt,
                                                    const float* __restrict__ bias,
                                                    const float* __restrict__ al,
                                                    const float* __restrict__ ar,
                                                    float* __restrict__ el4,
                                                    float* __restrict__ er4,
                                                    float* __restrict__ xf,
                                                    ushort_t* __restrict__ xb,
                                                    ushort_t* __restrict__ zb,
                                                    int nrows) {
    constexpr int N = NT * 16;
    const int lane = threadIdx.x & 63;
    const int wid = threadIdx.x >> 6;
    const int row0 = blockIdx.x * 64 + wid * 16;
    const int m = lane & 15;
    const int kg = lane >> 4;

    int rA = row0 + m;
    if (rA > nrows - 1) rA = nrows - 1;
    const ushort_t* arow = Ab + (size_t)rA * K + kg * 8;

    const f32x4 zero4 = {0.f, 0.f, 0.f, 0.f};
    f32x4 acc[NT];
#pragma unroll
    for (int n = 0; n < NT; ++n) acc[n] = zero4;

#pragma unroll
    for (int k0 = 0; k0 < K; k0 += 32) {
        bf16x8 a = *(const bf16x8*)(arow + k0);
#pragma unroll
        for (int n = 0; n < NT; ++n) {
            bf16x8 b = *(const bf16x8*)(Wt + (size_t)(n * 16 + m) * K + k0 + kg * 8);
            acc[n] = __builtin_amdgcn_mfma_f32_16x16x32_bf16(a, b, acc[n], 0, 0, 0);
        }
    }

    const int orow = row0 + kg * 4;

    if (ATTN) {
        float sl[NHEADS][4], sr[NHEADS][4];
#pragma unroll
        for (int h = 0; h < NHEADS; ++h)
#pragma unroll
            for (int r = 0; r < 4; ++r) { sl[h][r] = 0.f; sr[h][r] = 0.f; }
#pragma unroll
        for (int n = 0; n < NT; ++n) {
            float alv = al[n * 16 + m];
            float arv = ar[n * 16 + m];
            const int h = n >> 2;
#pragma unroll
            for (int r = 0; r < 4; ++r) {
                sl[h][r] = fmaf(acc[n][r], alv, sl[h][r]);
                sr[h][r] = fmaf(acc[n][r], arv, sr[h][r]);
            }
        }
#pragma unroll
        for (int off = 1; off < 16; off <<= 1) {
#pragma unroll
            for (int h = 0; h < NHEADS; ++h)
#pragma unroll
                for (int r = 0; r < 4; ++r) {
                    sl[h][r] += __shfl_xor(sl[h][r], off);
                    sr[h][r] += __shfl_xor(sr[h][r], off);
                }
        }
#pragma unroll
        for (int r = 0; r < 4; ++r) {
            int gr = orow + r;
            if (gr < nrows) {
#pragma unroll
                for (int n = 0; n < NT; ++n)
                    zb[(size_t)gr * N + n * 16 + m] = f2bf(acc[n][r]);
                if (m == 0) {
                    *(float4*)(el4 + (size_t)gr * 4) = make_float4(sl[0][r], sl[1][r], sl[2][r], 0.f);
                    *(float4*)(er4 + (size_t)gr * 4) = make_float4(sr[0][r], sr[1][r], sr[2][r], 0.f);
                }
            }
        }
    } else {
#pragma unroll
        for (int r = 0; r < 4; ++r) {
            int gr = orow + r;
            if (gr < nrows) {
#pragma unroll
                for (int n = 0; n < NT; ++n) {
                    float v = acc[n][r] + bias[n * 16 + m];
                    xf[(size_t)gr * N + n * 16 + m] = v;
                    xb[(size_t)gr * N + n * 16 + m] = f2bf(v);
                }
            }
        }
    }
}

// ---------------- CSR build ----------------
__global__ __launch_bounds__(256) void count_kernel(const int* __restrict__ dst, int* __restrict__ cnt) {
    int e = blockIdx.x * 256 + threadIdx.x;
    if (e < NE) atomicAdd(&cnt[dst[e]], 1);
}

__global__ __launch_bounds__(256) void scan_block_kernel(const int* __restrict__ cnt,
                                                         int* __restrict__ incl,
                                                         int* __restrict__ bsum, int n) {
    __shared__ int s[256];
    int tid = threadIdx.x;
    int i = blockIdx.x * 256 + tid;
    int v = (i < n) ? cnt[i] : 0;
    s[tid] = v;
    __syncthreads();
#pragma unroll
    for (int off = 1; off < 256; off <<= 1) {
        int add = (tid >= off) ? s[tid - off] : 0;
        __syncthreads();
        s[tid] += add;
        __syncthreads();
    }
    if (i < n) incl[i] = s[tid];
    if (tid == 255) bsum[blockIdx.x] = s[255];
}

__global__ __launch_bounds__(256) void scan_bsum_kernel(int* __restrict__ bsum, int nb) {
    __shared__ int s[256];
    int tid = threadIdx.x;
    int v = (tid < nb) ? bsum[tid] : 0;
    s[tid] = v;
    __syncthreads();
#pragma unroll
    for (int off = 1; off < 256; off <<= 1) {
        int add = (tid >= off) ? s[tid - off] : 0;
        __syncthreads();
        s[tid] += add;
        __syncthreads();
    }
    if (tid < nb) bsum[tid] = s[tid] - v;  // exclusive
}

__global__ __launch_bounds__(256) void finalize_rowptr_kernel(const int* __restrict__ incl,
                                                              const int* __restrict__ boff,
                                                              int* __restrict__ row_ptr, int n) {
    int i = blockIdx.x * 256 + threadIdx.x;
    if (i < n) row_ptr[i + 1] = incl[i] + boff[i >> 8];
    if (i == 0) row_ptr[0] = 0;
}

__global__ __launch_bounds__(256) void fill_kernel(const int* __restrict__ src,
                                                   const int* __restrict__ dst,
                                                   const int* __restrict__ row_ptr,
                                                   int* __restrict__ cur,
                                                   int* __restrict__ srcs_sorted) {
    int e = blockIdx.x * 256 + threadIdx.x;
    if (e < NE) {
        int d = dst[e];
        int pos = row_ptr[d] + atomicAdd(&cur[d], 1);
        srcs_sorted[pos] = src[e];
    }
}

// ---------------- aggregation: one wave per dst node, single pass, 4-deep MLP ----------------
// Chunk prologue (all 64 lanes): lane i computes exp-score p for edge c0+i, accumulates denom.
// Inner loop (lanes 0..47, 4 edges/iter): row indices via readlane -> SGPR base addressing,
// 4 independent 8B gathers in flight, then 16 FMAs. Lane l owns dims 4l..4l+3.
__global__ __launch_bounds__(256) void aggregate_kernel(const ushort_t* __restrict__ zb,
                                                        const float* __restrict__ el4,
                                                        const float* __restrict__ er4,
                                                        const int* __restrict__ row_ptr,
                                                        const int* __restrict__ srcs,
                                                        const float* __restrict__ bias,
                                                        ushort_t* __restrict__ yb) {
    int node = blockIdx.x * 4 + (threadIdx.x >> 6);
    int lane = threadIdx.x & 63;
    if (node >= NN) return;
    int s0 = row_ptr[node], s1 = row_ptr[node + 1];
    size_t o = (size_t)node * HD;
    const int h = lane >> 4;    // head for owned dims (lanes 0..47)
    const int loff = lane * 4;  // ushort offset (8B per lane)

    float4 erv = *(const float4*)(er4 + (size_t)node * 4);

    float d0 = 0.f, d1 = 0.f, d2 = 0.f;
    f32x4 a = {0.f, 0.f, 0.f, 0.f};

    for (int c0 = s0; c0 < s1; c0 += 64) {
        int i = c0 + lane;
        float p0 = 0.f, p1 = 0.f, p2 = 0.f;
        int s = 0;
        if (i < s1) {
            s = srcs[i];
            float4 elv = *(const float4*)(el4 + (size_t)s * 4);
            float e0 = elv.x + erv.x, e1 = elv.y + erv.y, e2 = elv.z + erv.z;
            e0 = e0 > 0.f ? e0 : 0.2f * e0;
            e1 = e1 > 0.f ? e1 : 0.2f * e1;
            e2 = e2 > 0.f ? e2 : 0.2f * e2;
            p0 = __expf(fminf(e0, 60.f));
            p1 = __expf(fminf(e1, 60.f));
            p2 = __expf(fminf(e2, 60.f));
        }
        d0 += p0; d1 += p1; d2 += p2;
        int nch = s1 - c0; if (nch > 64) nch = 64;
        if (lane < 48) {
            for (int j = 0; j < nch; j += 4) {
                // 4 uniform row bases (SGPR) — overshoot edges have p=0, s=0 (load row 0 * 0)
                int sj0 = __builtin_amdgcn_readlane(s, j);
                int sj1 = __builtin_amdgcn_readlane(s, j + 1);
                int sj2 = __builtin_amdgcn_readlane(s, j + 2);
                int sj3 = __builtin_amdgcn_readlane(s, j + 3);
                const ushort_t* r0 = zb + (size_t)sj0 * HD;
                const ushort_t* r1 = zb + (size_t)sj1 * HD;
                const ushort_t* r2 = zb + (size_t)sj2 * HD;
                const ushort_t* r3 = zb + (size_t)sj3 * HD;
                ushort4 zv0 = *(const ushort4*)(r0 + loff);
                ushort4 zv1 = *(const ushort4*)(r1 + loff);
                ushort4 zv2 = *(const ushort4*)(r2 + loff);
                ushort4 zv3 = *(const ushort4*)(r3 + loff);
                float qa, qb, qc, q0, q1, q2, q3;
                qa = readlane_f(p0, j); qb = readlane_f(p1, j); qc = readlane_f(p2, j);
                q0 = (h == 0) ? qa : ((h == 1) ? qb : qc);
                qa = readlane_f(p0, j + 1); qb = readlane_f(p1, j + 1); qc = readlane_f(p2, j + 1);
                q1 = (h == 0) ? qa : ((h == 1) ? qb : qc);
                qa = readlane_f(p0, j + 2); qb = readlane_f(p1, j + 2); qc = readlane_f(p2, j + 2);
                q2 = (h == 0) ? qa : ((h == 1) ? qb : qc);
                qa = readlane_f(p0, j + 3); qb = readlane_f(p1, j + 3); qc = readlane_f(p2, j + 3);
                q3 = (h == 0) ? qa : ((h == 1) ? qb : qc);
                a[0] = fmaf(q0, bf2f(zv0.x), a[0]);
                a[1] = fmaf(q0, bf2f(zv0.y), a[1]);
                a[2] = fmaf(q0, bf2f(zv0.z), a[2]);
                a[3] = fmaf(q0, bf2f(zv0.w), a[3]);
                a[0] = fmaf(q1, bf2f(zv1.x), a[0]);
                a[1] = fmaf(q1, bf2f(zv1.y), a[1]);
                a[2] = fmaf(q1, bf2f(zv1.z), a[2]);
                a[3] = fmaf(q1, bf2f(zv1.w), a[3]);
                a[0] = fmaf(q2, bf2f(zv2.x), a[0]);
                a[1] = fmaf(q2, bf2f(zv2.y), a[1]);
                a[2] = fmaf(q2, bf2f(zv2.z), a[2]);
                a[3] = fmaf(q2, bf2f(zv2.w), a[3]);
                a[0] = fmaf(q3, bf2f(zv3.x), a[0]);
                a[1] = fmaf(q3, bf2f(zv3.y), a[1]);
                a[2] = fmaf(q3, bf2f(zv3.z), a[2]);
                a[3] = fmaf(q3, bf2f(zv3.w), a[3]);
            }
        }
    }
#pragma unroll
    for (int off = 32; off > 0; off >>= 1) {
        d0 += __shfl_xor(d0, off);
        d1 += __shfl_xor(d1, off);
        d2 += __shfl_xor(d2, off);
    }

    if (lane < 48) {
        float dd = (h == 0) ? d0 : ((h == 1) ? d1 : d2);
        float rinv = 1.0f / dd;
        float4 bb = *(const float4*)(bias + loff);
        ushort4 ov;
        ov.x = f2bf(a[0] * rinv + bb.x);
        ov.y = f2bf(a[1] * rinv + bb.y);
        ov.z = f2bf(a[2] * rinv + bb.z);
        ov.w = f2bf(a[3] * rinv + bb.w);
        *(ushort4*)(yb + o + loff) = ov;
    }
}

// ---------------- pooling ----------------
__global__ __launch_bounds__(256) void pool_kernel(const float* __restrict__ x,
                                                   const int* __restrict__ gid,
                                                   float* __restrict__ gsum,
                                                   int* __restrict__ gcnt) {
    int w = blockIdx.x * 4 + (threadIdx.x >> 6);
    int lane = threadIdx.x & 63;
    int n0 = w * 16;
    if (n0 >= NN) return;
    int n1 = n0 + 16; if (n1 > NN) n1 = NN;
    int curg = gid[n0];
    float acc = 0.f;
    int cl = 0;
    for (int n = n0; n < n1; ++n) {
        int g = gid[n];
        if (g != curg) {
            atomicAdd(&gsum[curg * 64 + lane], acc);
            if (lane == 0) atomicAdd(&gcnt[curg], cl);
            acc = 0.f; cl = 0; curg = g;
        }
        acc += x[(size_t)n * 64 + lane];
        cl++;
    }
    atomicAdd(&gsum[curg * 64 + lane], acc);
    if (lane == 0) atomicAdd(&gcnt[curg], cl);
}

__global__ __launch_bounds__(256) void pool_final_kernel(const float* __restrict__ gsum,
                                                         const int* __restrict__ gcnt,
                                                         float* __restrict__ out) {
    int idx = blockIdx.x * 256 + threadIdx.x;
    if (idx < NG * 64) {
        int g = idx >> 6;
        float c = (float)gcnt[g];
        out[idx] = gsum[idx] / fmaxf(c, 1.0f);
    }
}

// ---------------- launch ----------------
extern "C" void kernel_launch(void* const* d_in, const int* in_sizes, int n_in,
                              void* d_out, int out_size, void* d_ws, size_t ws_size,
                              hipStream_t stream) {
    const float* feats = (const float*)d_in[0];
    const int* src = (const int*)d_in[1];
    const int* dst = (const int*)d_in[2];
    const int* gid = (const int*)d_in[3];
    const float* W1 = (const float*)d_in[4];
    const float* al1 = (const float*)d_in[5];
    const float* ar1 = (const float*)d_in[6];
    const float* b1 = (const float*)d_in[7];
    const float* W2 = (const float*)d_in[8];
    const float* al2 = (const float*)d_in[9];
    const float* ar2 = (const float*)d_in[10];
    const float* b2 = (const float*)d_in[11];
    const float* Wl = (const float*)d_in[12];
    const float* bl = (const float*)d_in[13];
    float* out = (float*)d_out;

    size_t off = 0;
    auto alloc = [&](size_t bytes) -> char* {
        char* p = (char*)d_ws + off;
        off += (bytes + 255) & ~(size_t)255;
        return p;
    };
    ushort_t* featsb = (ushort_t*)alloc((size_t)NN * FIN * 2);
    ushort_t* zb = (ushort_t*)alloc((size_t)NN * HD * 2);
    ushort_t* yb = (ushort_t*)alloc((size_t)NN * HD * 2);
    ushort_t* xb = (ushort_t*)alloc((size_t)NN * 64 * 2);
    float* xf = (float*)alloc((size_t)NN * 64 * 4);
    float* el4 = (float*)alloc((size_t)NN * 4 * 4);
    float* er4 = (float*)alloc((size_t)NN * 4 * 4);
    ushort_t* W1t = (ushort_t*)alloc((size_t)HD * FIN * 2);  // [192][128]
    ushort_t* W2t = (ushort_t*)alloc((size_t)HD * 64 * 2);   // [192][64]
    ushort_t* Wlt = (ushort_t*)alloc((size_t)64 * HD * 2);   // [64][192]
    int* row_ptr = (int*)alloc((size_t)(NN + 1) * 4);
    int* cnt = (int*)alloc((size_t)NN * 4);
    int* incl = (int*)alloc((size_t)NN * 4);
    int* bsum = (int*)alloc(256 * 4);
    int* srcs = (int*)alloc((size_t)NE * 4);
    float* gsum = (float*)alloc((size_t)NG * 64 * 4);
    int* gcnt = (int*)alloc((size_t)NG * 4);

    const int nbScan = (NN + 255) / 256;
    const int gridE = (NE + 255) / 256;
    const int gridNode = (NN + 3) / 4;
    const int gridGemm = (NN + 63) / 64;

    // ---- input conversions (bf16) ----
    fconv_kernel<<<(NN * FIN / 4 + 255) / 256, 256, 0, stream>>>(feats, featsb, NN * FIN / 4);
    wconv_kernel<<<(FIN * HD + 255) / 256, 256, 0, stream>>>(W1, W1t, FIN, HD);
    wconv_kernel<<<(64 * HD + 255) / 256, 256, 0, stream>>>(W2, W2t, 64, HD);
    wconv_kernel<<<(HD * 64 + 255) / 256, 256, 0, stream>>>(Wl, Wlt, HD, 64);

    // ---- CSR build (shared by all 3 convs) ----
    hipMemsetAsync(cnt, 0, (size_t)NN * 4, stream);
    count_kernel<<<gridE, 256, 0, stream>>>(dst, cnt);
    scan_block_kernel<<<nbScan, 256, 0, stream>>>(cnt, incl, bsum, NN);
    scan_bsum_kernel<<<1, 256, 0, stream>>>(bsum, nbScan);
    finalize_rowptr_kernel<<<nbScan, 256, 0, stream>>>(incl, bsum, row_ptr, NN);
    hipMemsetAsync(cnt, 0, (size_t)NN * 4, stream);
    fill_kernel<<<gridE, 256, 0, stream>>>(src, dst, row_ptr, cnt, srcs);

    // ---- conv1 ----
    mgemm_kernel<FIN, 12, 1><<<gridGemm, 256, 0, stream>>>(featsb, W1t, nullptr, al1, ar1,
                                                           el4, er4, nullptr, nullptr, zb, NN);
    aggregate_kernel<<<gridNode, 256, 0, stream>>>(zb, el4, er4, row_ptr, srcs, b1, yb);
    mgemm_kernel<HD, 4, 0><<<gridGemm, 256, 0, stream>>>(yb, Wlt, bl, nullptr, nullptr,
                                                         nullptr, nullptr, xf, xb, nullptr, NN);

    // ---- conv2, conv3 ----
    for (int it = 0; it < 2; ++it) {
        mgemm_kernel<64, 12, 1><<<gridGemm, 256, 0, stream>>>(xb, W2t, nullptr, al2, ar2,
                                                              el4, er4, nullptr, nullptr, zb, NN);
        aggregate_kernel<<<gridNode, 256, 0, stream>>>(zb, el4, er4, row_ptr, srcs, b2, yb);
        mgemm_kernel<HD, 4, 0><<<gridGemm, 256, 0, stream>>>(yb, Wlt, bl, nullptr, nullptr,
                                                             nullptr, nullptr, xf, xb, nullptr, NN);
    }

    // ---- avg pooling ----
    hipMemsetAsync(gsum, 0, (size_t)NG * 64 * 4 + (size_t)NG * 4, stream);
    pool_kernel<<<(NN / 16 + 3) / 4 + 1, 256, 0, stream>>>(xf, gid, gsum, gcnt);
    pool_final_kernel<<<(NG * 64 + 255) / 256, 256, 0, stream>>>(gsum, gcnt, out);
}

// Round 9
// 436.252 us; speedup vs baseline: 2.4555x; 1.0834x over previous
//
#include <hip/hip_runtime.h>
#include <hip/hip_bf16.h>

#define NN 50000
#define NE 800000
#define FIN 128
#define NHEADS 3
#define NG 1024
#define HD 192

typedef unsigned short ushort_t;
typedef __bf16 bf16x8 __attribute__((ext_vector_type(8)));
typedef float f32x4 __attribute__((ext_vector_type(4)));

__device__ __forceinline__ float bf2f(ushort_t u) {
    union { unsigned int i; float f; } c;
    c.i = ((unsigned int)u) << 16;
    return c.f;
}
__device__ __forceinline__ ushort_t f2bf(float f) {
    __hip_bfloat16 h = __float2bfloat16(f);
    return *reinterpret_cast<ushort_t*>(&h);
}

// ---------------- feats f32 -> bf16 (vectorized x4) ----------------
__global__ __launch_bounds__(256) void fconv_kernel(const float* __restrict__ f,
                                                    ushort_t* __restrict__ fb, int n4) {
    int i = blockIdx.x * 256 + threadIdx.x;
    if (i < n4) {
        float4 v = ((const float4*)f)[i];
        ushort4 o;
        o.x = f2bf(v.x); o.y = f2bf(v.y); o.z = f2bf(v.z); o.w = f2bf(v.w);
        ((ushort4*)fb)[i] = o;
    }
}

// ---------------- weight W[K][N] f32 -> Wt[N][K] bf16 ----------------
__global__ __launch_bounds__(256) void wconv_kernel(const float* __restrict__ W,
                                                    ushort_t* __restrict__ Wt, int K, int N) {
    int idx = blockIdx.x * 256 + threadIdx.x;
    if (idx < K * N) {
        int k = idx / N, n = idx - k * N;
        Wt[n * K + k] = f2bf(W[idx]);
    }
}

// ---------------- MFMA GEMM: C[nrows,NT*16] = Ab[nrows,K] @ Wt^T ----------------
// 256 thr = 4 waves, 64 rows/block, wave -> 16 rows x N cols. Register-only, no LDS.
// A frag: row = lane&15, k = (lane>>4)*8+j (contiguous 16B). B frag from Wt[N][K].
// C/D: col=lane&15, row=(lane>>4)*4+reg (verified m89 mapping).
template<int K, int NT, int ATTN>
__global__ __launch_bounds__(256) void mgemm_kernel(const ushort_t* __restrict__ Ab,
                                                    const ushort_t* __restrict__ Wt,
                                                    const float* __restrict__ bias,
                                                    const float* __restrict__ al,
                                                    const float* __restrict__ ar,
                                                    float* __restrict__ el4,
                                                    float* __restrict__ er4,
                                                    float* __restrict__ xf,
                                                    ushort_t* __restrict__ xb,
                                                    ushort_t* __restrict__ zb,
                                                    int nrows) {
    constexpr int N = NT * 16;
    const int lane = threadIdx.x & 63;
    const int wid = threadIdx.x >> 6;
    const int row0 = blockIdx.x * 64 + wid * 16;
    const int m = lane & 15;
    const int kg = lane >> 4;

    int rA = row0 + m;
    if (rA > nrows - 1) rA = nrows - 1;
    const ushort_t* arow = Ab + (size_t)rA * K + kg * 8;

    const f32x4 zero4 = {0.f, 0.f, 0.f, 0.f};
    f32x4 acc[NT];
#pragma unroll
    for (int n = 0; n < NT; ++n) acc[n] = zero4;

#pragma unroll
    for (int k0 = 0; k0 < K; k0 += 32) {
        bf16x8 a = *(const bf16x8*)(arow + k0);
#pragma unroll
        for (int n = 0; n < NT; ++n) {
            bf16x8 b = *(const bf16x8*)(Wt + (size_t)(n * 16 + m) * K + k0 + kg * 8);
            acc[n] = __builtin_amdgcn_mfma_f32_16x16x32_bf16(a, b, acc[n], 0, 0, 0);
        }
    }

    const int orow = row0 + kg * 4;

    if (ATTN) {
        float sl[NHEADS][4], sr[NHEADS][4];
#pragma unroll
        for (int h = 0; h < NHEADS; ++h)
#pragma unroll
            for (int r = 0; r < 4; ++r) { sl[h][r] = 0.f; sr[h][r] = 0.f; }
#pragma unroll
        for (int n = 0; n < NT; ++n) {
            float alv = al[n * 16 + m];
            float arv = ar[n * 16 + m];
            const int h = n >> 2;
#pragma unroll
            for (int r = 0; r < 4; ++r) {
                sl[h][r] = fmaf(acc[n][r], alv, sl[h][r]);
                sr[h][r] = fmaf(acc[n][r], arv, sr[h][r]);
            }
        }
#pragma unroll
        for (int off = 1; off < 16; off <<= 1) {
#pragma unroll
            for (int h = 0; h < NHEADS; ++h)
#pragma unroll
                for (int r = 0; r < 4; ++r) {
                    sl[h][r] += __shfl_xor(sl[h][r], off);
                    sr[h][r] += __shfl_xor(sr[h][r], off);
                }
        }
#pragma unroll
        for (int r = 0; r < 4; ++r) {
            int gr = orow + r;
            if (gr < nrows) {
#pragma unroll
                for (int n = 0; n < NT; ++n)
                    zb[(size_t)gr * N + n * 16 + m] = f2bf(acc[n][r]);
                if (m == 0) {
                    *(float4*)(el4 + (size_t)gr * 4) = make_float4(sl[0][r], sl[1][r], sl[2][r], 0.f);
                    *(float4*)(er4 + (size_t)gr * 4) = make_float4(sr[0][r], sr[1][r], sr[2][r], 0.f);
                }
            }
        }
    } else {
#pragma unroll
        for (int r = 0; r < 4; ++r) {
            int gr = orow + r;
            if (gr < nrows) {
#pragma unroll
                for (int n = 0; n < NT; ++n) {
                    float v = acc[n][r] + bias[n * 16 + m];
                    xf[(size_t)gr * N + n * 16 + m] = v;
                    xb[(size_t)gr * N + n * 16 + m] = f2bf(v);
                }
            }
        }
    }
}

// ---------------- CSR build ----------------
// count: 4 edges/thread (independent atomic chains); store rank = old count.
__global__ __launch_bounds__(256) void count_kernel(const int* __restrict__ dst,
                                                    int* __restrict__ cnt,
                                                    int* __restrict__ rank) {
    int e0 = blockIdx.x * 1024 + threadIdx.x;
#pragma unroll
    for (int k = 0; k < 4; ++k) {
        int e = e0 + k * 256;
        if (e < NE) rank[e] = atomicAdd(&cnt[dst[e]], 1);
    }
}

__global__ __launch_bounds__(256) void scan_block_kernel(const int* __restrict__ cnt,
                                                         int* __restrict__ incl,
                                                         int* __restrict__ bsum, int n) {
    __shared__ int s[256];
    int tid = threadIdx.x;
    int i = blockIdx.x * 256 + tid;
    int v = (i < n) ? cnt[i] : 0;
    s[tid] = v;
    __syncthreads();
#pragma unroll
    for (int off = 1; off < 256; off <<= 1) {
        int add = (tid >= off) ? s[tid - off] : 0;
        __syncthreads();
        s[tid] += add;
        __syncthreads();
    }
    if (i < n) incl[i] = s[tid];
    if (tid == 255) bsum[blockIdx.x] = s[255];
}

__global__ __launch_bounds__(256) void scan_bsum_kernel(int* __restrict__ bsum, int nb) {
    __shared__ int s[256];
    int tid = threadIdx.x;
    int v = (tid < nb) ? bsum[tid] : 0;
    s[tid] = v;
    __syncthreads();
#pragma unroll
    for (int off = 1; off < 256; off <<= 1) {
        int add = (tid >= off) ? s[tid - off] : 0;
        __syncthreads();
        s[tid] += add;
        __syncthreads();
    }
    if (tid < nb) bsum[tid] = s[tid] - v;  // exclusive
}

__global__ __launch_bounds__(256) void finalize_rowptr_kernel(const int* __restrict__ incl,
                                                              const int* __restrict__ boff,
                                                              int* __restrict__ row_ptr, int n) {
    int i = blockIdx.x * 256 + threadIdx.x;
    if (i < n) row_ptr[i + 1] = incl[i] + boff[i >> 8];
    if (i == 0) row_ptr[0] = 0;
}

// fill: atomic-free scatter using precomputed rank.
__global__ __launch_bounds__(256) void fill_kernel(const int* __restrict__ src,
                                                   const int* __restrict__ dst,
                                                   const int* __restrict__ row_ptr,
                                                   const int* __restrict__ rank,
                                                   int* __restrict__ srcs_sorted) {
    int e = blockIdx.x * 256 + threadIdx.x;
    if (e < NE) {
        srcs_sorted[row_ptr[dst[e]] + rank[e]] = src[e];
    }
}

// ---------------- aggregation: one wave per dst node, single pass ----------------
// Chunk prologue (all 64 lanes): lane i computes exp-scores p0..p2 for edge c0+i,
// accumulates denom, writes p to wave-local LDS plds[wid][3][64].
// Inner loop (lanes 0..47, 4 edges/iter): row bases via readlane (SGPR addressing),
// q values via one ds_read_b128 from own head's plds row. Lane l owns dims 4l..4l+3.
__global__ __launch_bounds__(256) void aggregate_kernel(const ushort_t* __restrict__ zb,
                                                        const float* __restrict__ el4,
                                                        const float* __restrict__ er4,
                                                        const int* __restrict__ row_ptr,
                                                        const int* __restrict__ srcs,
                                                        const float* __restrict__ bias,
                                                        ushort_t* __restrict__ yb) {
    __shared__ float plds[4][NHEADS][64];
    int node = blockIdx.x * 4 + (threadIdx.x >> 6);
    int lane = threadIdx.x & 63;
    if (node >= NN) return;
    int s0 = row_ptr[node], s1 = row_ptr[node + 1];
    size_t o = (size_t)node * HD;
    const int wid = threadIdx.x >> 6;
    const int h = lane >> 4;    // head for owned dims (lanes 0..47)
    const int loff = lane * 4;  // ushort offset (8B per lane)

    float4 erv = *(const float4*)(er4 + (size_t)node * 4);

    float d0 = 0.f, d1 = 0.f, d2 = 0.f;
    f32x4 a = {0.f, 0.f, 0.f, 0.f};

    for (int c0 = s0; c0 < s1; c0 += 64) {
        int i = c0 + lane;
        float p0 = 0.f, p1 = 0.f, p2 = 0.f;
        int s = 0;
        if (i < s1) {
            s = srcs[i];
            float4 elv = *(const float4*)(el4 + (size_t)s * 4);
            float e0 = elv.x + erv.x, e1 = elv.y + erv.y, e2 = elv.z + erv.z;
            e0 = e0 > 0.f ? e0 : 0.2f * e0;
            e1 = e1 > 0.f ? e1 : 0.2f * e1;
            e2 = e2 > 0.f ? e2 : 0.2f * e2;
            p0 = __expf(fminf(e0, 60.f));
            p1 = __expf(fminf(e1, 60.f));
            p2 = __expf(fminf(e2, 60.f));
        }
        d0 += p0; d1 += p1; d2 += p2;
        plds[wid][0][lane] = p0;
        plds[wid][1][lane] = p1;
        plds[wid][2][lane] = p2;
        // wave-local LDS: order write->read within the wave (no __syncthreads;
        // divergent per-wave loop). The waitcnt drains the ds_writes.
        asm volatile("s_waitcnt lgkmcnt(0)" ::: "memory");
        int nch = s1 - c0; if (nch > 64) nch = 64;
        if (lane < 48) {
            const float* prow = &plds[wid][h][0];
            for (int j = 0; j < nch; j += 4) {
                int sj0 = __builtin_amdgcn_readlane(s, j);
                int sj1 = __builtin_amdgcn_readlane(s, j + 1);
                int sj2 = __builtin_amdgcn_readlane(s, j + 2);
                int sj3 = __builtin_amdgcn_readlane(s, j + 3);
                const ushort_t* r0 = zb + (size_t)sj0 * HD;
                const ushort_t* r1 = zb + (size_t)sj1 * HD;
                const ushort_t* r2 = zb + (size_t)sj2 * HD;
                const ushort_t* r3 = zb + (size_t)sj3 * HD;
                ushort4 zv0 = *(const ushort4*)(r0 + loff);
                ushort4 zv1 = *(const ushort4*)(r1 + loff);
                ushort4 zv2 = *(const ushort4*)(r2 + loff);
                ushort4 zv3 = *(const ushort4*)(r3 + loff);
                float4 q = *(const float4*)(prow + j);   // ds_read_b128
                a[0] = fmaf(q.x, bf2f(zv0.x), a[0]);
                a[1] = fmaf(q.x, bf2f(zv0.y), a[1]);
                a[2] = fmaf(q.x, bf2f(zv0.z), a[2]);
                a[3] = fmaf(q.x, bf2f(zv0.w), a[3]);
                a[0] = fmaf(q.y, bf2f(zv1.x), a[0]);
                a[1] = fmaf(q.y, bf2f(zv1.y), a[1]);
                a[2] = fmaf(q.y, bf2f(zv1.z), a[2]);
                a[3] = fmaf(q.y, bf2f(zv1.w), a[3]);
                a[0] = fmaf(q.z, bf2f(zv2.x), a[0]);
                a[1] = fmaf(q.z, bf2f(zv2.y), a[1]);
                a[2] = fmaf(q.z, bf2f(zv2.z), a[2]);
                a[3] = fmaf(q.z, bf2f(zv2.w), a[3]);
                a[0] = fmaf(q.w, bf2f(zv3.x), a[0]);
                a[1] = fmaf(q.w, bf2f(zv3.y), a[1]);
                a[2] = fmaf(q.w, bf2f(zv3.z), a[2]);
                a[3] = fmaf(q.w, bf2f(zv3.w), a[3]);
            }
        }
    }
#pragma unroll
    for (int off = 32; off > 0; off >>= 1) {
        d0 += __shfl_xor(d0, off);
        d1 += __shfl_xor(d1, off);
        d2 += __shfl_xor(d2, off);
    }

    if (lane < 48) {
        float dd = (h == 0) ? d0 : ((h == 1) ? d1 : d2);
        float rinv = 1.0f / dd;
        float4 bb = *(const float4*)(bias + loff);
        ushort4 ov;
        ov.x = f2bf(a[0] * rinv + bb.x);
        ov.y = f2bf(a[1] * rinv + bb.y);
        ov.z = f2bf(a[2] * rinv + bb.z);
        ov.w = f2bf(a[3] * rinv + bb.w);
        *(ushort4*)(yb + o + loff) = ov;
    }
}

// ---------------- pooling ----------------
__global__ __launch_bounds__(256) void pool_kernel(const float* __restrict__ x,
                                                   const int* __restrict__ gid,
                                                   float* __restrict__ gsum,
                                                   int* __restrict__ gcnt) {
    int w = blockIdx.x * 4 + (threadIdx.x >> 6);
    int lane = threadIdx.x & 63;
    int n0 = w * 16;
    if (n0 >= NN) return;
    int n1 = n0 + 16; if (n1 > NN) n1 = NN;
    int curg = gid[n0];
    float acc = 0.f;
    int cl = 0;
    for (int n = n0; n < n1; ++n) {
        int g = gid[n];
        if (g != curg) {
            atomicAdd(&gsum[curg * 64 + lane], acc);
            if (lane == 0) atomicAdd(&gcnt[curg], cl);
            acc = 0.f; cl = 0; curg = g;
        }
        acc += x[(size_t)n * 64 + lane];
        cl++;
    }
    atomicAdd(&gsum[curg * 64 + lane], acc);
    if (lane == 0) atomicAdd(&gcnt[curg], cl);
}

__global__ __launch_bounds__(256) void pool_final_kernel(const float* __restrict__ gsum,
                                                         const int* __restrict__ gcnt,
                                                         float* __restrict__ out) {
    int idx = blockIdx.x * 256 + threadIdx.x;
    if (idx < NG * 64) {
        int g = idx >> 6;
        float c = (float)gcnt[g];
        out[idx] = gsum[idx] / fmaxf(c, 1.0f);
    }
}

// ---------------- launch ----------------
extern "C" void kernel_launch(void* const* d_in, const int* in_sizes, int n_in,
                              void* d_out, int out_size, void* d_ws, size_t ws_size,
                              hipStream_t stream) {
    const float* feats = (const float*)d_in[0];
    const int* src = (const int*)d_in[1];
    const int* dst = (const int*)d_in[2];
    const int* gid = (const int*)d_in[3];
    const float* W1 = (const float*)d_in[4];
    const float* al1 = (const float*)d_in[5];
    const float* ar1 = (const float*)d_in[6];
    const float* b1 = (const float*)d_in[7];
    const float* W2 = (const float*)d_in[8];
    const float* al2 = (const float*)d_in[9];
    const float* ar2 = (const float*)d_in[10];
    const float* b2 = (const float*)d_in[11];
    const float* Wl = (const float*)d_in[12];
    const float* bl = (const float*)d_in[13];
    float* out = (float*)d_out;

    size_t off = 0;
    auto alloc = [&](size_t bytes) -> char* {
        char* p = (char*)d_ws + off;
        off += (bytes + 255) & ~(size_t)255;
        return p;
    };
    ushort_t* featsb = (ushort_t*)alloc((size_t)NN * FIN * 2);
    ushort_t* zb = (ushort_t*)alloc((size_t)NN * HD * 2);
    ushort_t* yb = (ushort_t*)alloc((size_t)NN * HD * 2);
    ushort_t* xb = (ushort_t*)alloc((size_t)NN * 64 * 2);
    float* xf = (float*)alloc((size_t)NN * 64 * 4);
    float* el4 = (float*)alloc((size_t)NN * 4 * 4);
    float* er4 = (float*)alloc((size_t)NN * 4 * 4);
    ushort_t* W1t = (ushort_t*)alloc((size_t)HD * FIN * 2);  // [192][128]
    ushort_t* W2t = (ushort_t*)alloc((size_t)HD * 64 * 2);   // [192][64]
    ushort_t* Wlt = (ushort_t*)alloc((size_t)64 * HD * 2);   // [64][192]
    int* row_ptr = (int*)alloc((size_t)(NN + 1) * 4);
    int* cnt = (int*)alloc((size_t)NN * 4);
    int* incl = (int*)alloc((size_t)NN * 4);
    int* bsum = (int*)alloc(256 * 4);
    int* rank = (int*)alloc((size_t)NE * 4);
    int* srcs = (int*)alloc((size_t)NE * 4);
    float* gsum = (float*)alloc((size_t)NG * 64 * 4);
    int* gcnt = (int*)alloc((size_t)NG * 4);

    const int nbScan = (NN + 255) / 256;
    const int gridE = (NE + 255) / 256;
    const int gridNode = (NN + 3) / 4;
    const int gridGemm = (NN + 63) / 64;

    // ---- input conversions (bf16) ----
    fconv_kernel<<<(NN * FIN / 4 + 255) / 256, 256, 0, stream>>>(feats, featsb, NN * FIN / 4);
    wconv_kernel<<<(FIN * HD + 255) / 256, 256, 0, stream>>>(W1, W1t, FIN, HD);
    wconv_kernel<<<(64 * HD + 255) / 256, 256, 0, stream>>>(W2, W2t, 64, HD);
    wconv_kernel<<<(HD * 64 + 255) / 256, 256, 0, stream>>>(Wl, Wlt, HD, 64);

    // ---- CSR build (shared by all 3 convs) ----
    hipMemsetAsync(cnt, 0, (size_t)NN * 4, stream);
    count_kernel<<<(NE + 1023) / 1024, 256, 0, stream>>>(dst, cnt, rank);
    scan_block_kernel<<<nbScan, 256, 0, stream>>>(cnt, incl, bsum, NN);
    scan_bsum_kernel<<<1, 256, 0, stream>>>(bsum, nbScan);
    finalize_rowptr_kernel<<<nbScan, 256, 0, stream>>>(incl, bsum, row_ptr, NN);
    fill_kernel<<<gridE, 256, 0, stream>>>(src, dst, row_ptr, rank, srcs);

    // ---- conv1 ----
    mgemm_kernel<FIN, 12, 1><<<gridGemm, 256, 0, stream>>>(featsb, W1t, nullptr, al1, ar1,
                                                           el4, er4, nullptr, nullptr, zb, NN);
    aggregate_kernel<<<gridNode, 256, 0, stream>>>(zb, el4, er4, row_ptr, srcs, b1, yb);
    mgemm_kernel<HD, 4, 0><<<gridGemm, 256, 0, stream>>>(yb, Wlt, bl, nullptr, nullptr,
                                                         nullptr, nullptr, xf, xb, nullptr, NN);

    // ---- conv2, conv3 ----
    for (int it = 0; it < 2; ++it) {
        mgemm_kernel<64, 12, 1><<<gridGemm, 256, 0, stream>>>(xb, W2t, nullptr, al2, ar2,
                                                              el4, er4, nullptr, nullptr, zb, NN);
        aggregate_kernel<<<gridNode, 256, 0, stream>>>(zb, el4, er4, row_ptr, srcs, b2, yb);
        mgemm_kernel<HD, 4, 0><<<gridGemm, 256, 0, stream>>>(yb, Wlt, bl, nullptr, nullptr,
                                                             nullptr, nullptr, xf, xb, nullptr, NN);
    }

    // ---- avg pooling ----
    hipMemsetAsync(gsum, 0, (size_t)NG * 64 * 4 + (size_t)NG * 4, stream);
    pool_kernel<<<(NN / 16 + 3) / 4 + 1, 256, 0, stream>>>(xf, gid, gsum, gcnt);
    pool_final_kernel<<<(NG * 64 + 255) / 256, 256, 0, stream>>>(gsum, gcnt, out);
}

// Round 10
// 418.067 us; speedup vs baseline: 2.5623x; 1.0435x over previous
//
#include <hip/hip_runtime.h>
#include <hip/hip_bf16.h>

#define NN 50000
#define NE 800000
#define FIN 128
#define NHEADS 3
#define NG 1024
#define HD 192

typedef unsigned short ushort_t;
typedef __bf16 bf16x8 __attribute__((ext_vector_type(8)));
typedef float f32x4 __attribute__((ext_vector_type(4)));

__device__ __forceinline__ float bf2f(ushort_t u) {
    union { unsigned int i; float f; } c;
    c.i = ((unsigned int)u) << 16;
    return c.f;
}
__device__ __forceinline__ ushort_t f2bf(float f) {
    __hip_bfloat16 h = __float2bfloat16(f);
    return *reinterpret_cast<ushort_t*>(&h);
}

// ---------------- fused conversions: feats f32->bf16 + 3 weight transposes ----------------
#define F4 (NN * FIN / 4)
#define W1E (FIN * HD)
#define W2E (64 * HD)
#define WLE (HD * 64)
__global__ __launch_bounds__(256) void conv_all_kernel(const float* __restrict__ feats,
                                                       const float* __restrict__ W1,
                                                       const float* __restrict__ W2,
                                                       const float* __restrict__ Wl,
                                                       ushort_t* __restrict__ featsb,
                                                       ushort_t* __restrict__ W1t,
                                                       ushort_t* __restrict__ W2t,
                                                       ushort_t* __restrict__ Wlt) {
    int i = blockIdx.x * 256 + threadIdx.x;
    if (i < F4) {
        float4 v = ((const float4*)feats)[i];
        ushort4 o;
        o.x = f2bf(v.x); o.y = f2bf(v.y); o.z = f2bf(v.z); o.w = f2bf(v.w);
        ((ushort4*)featsb)[i] = o;
        return;
    }
    int t = i - F4;
    if (t < W1E) {  // W1[k][n] -> W1t[n][k], K=FIN, N=HD
        int k = t / HD, n = t - k * HD;
        W1t[n * FIN + k] = f2bf(W1[t]);
        return;
    }
    t -= W1E;
    if (t < W2E) {  // K=64, N=HD
        int k = t / HD, n = t - k * HD;
        W2t[n * 64 + k] = f2bf(W2[t]);
        return;
    }
    t -= W2E;
    if (t < WLE) {  // K=HD, N=64
        int k = t / 64, n = t - k * 64;
        Wlt[n * HD + k] = f2bf(Wl[t]);
    }
}

// ---------------- MFMA GEMM: C[nrows,NT*16] = Ab[nrows,K] @ Wt^T ----------------
// 256 thr = 4 waves, 64 rows/block, wave -> 16 rows x N cols. Register-only, no LDS.
// A frag: row = lane&15, k = (lane>>4)*8+j (contiguous 16B). B frag from Wt[N][K].
// C/D: col=lane&15, row=(lane>>4)*4+reg (verified m89 mapping).
// ATTN=1: write zb bf16 + el4/er4. ATTN=0: xb = bf16(acc+bias) only.
template<int K, int NT, int ATTN>
__global__ __launch_bounds__(256) void mgemm_kernel(const ushort_t* __restrict__ Ab,
                                                    const ushort_t* __restrict__ Wt,
                                                    const float* __restrict__ bias,
                                                    const float* __restrict__ al,
                                                    const float* __restrict__ ar,
                                                    float* __restrict__ el4,
                                                    float* __restrict__ er4,
                                                    ushort_t* __restrict__ xb,
                                                    ushort_t* __restrict__ zb,
                                                    int nrows) {
    constexpr int N = NT * 16;
    const int lane = threadIdx.x & 63;
    const int wid = threadIdx.x >> 6;
    const int row0 = blockIdx.x * 64 + wid * 16;
    const int m = lane & 15;
    const int kg = lane >> 4;

    int rA = row0 + m;
    if (rA > nrows - 1) rA = nrows - 1;
    const ushort_t* arow = Ab + (size_t)rA * K + kg * 8;

    const f32x4 zero4 = {0.f, 0.f, 0.f, 0.f};
    f32x4 acc[NT];
#pragma unroll
    for (int n = 0; n < NT; ++n) acc[n] = zero4;

#pragma unroll
    for (int k0 = 0; k0 < K; k0 += 32) {
        bf16x8 a = *(const bf16x8*)(arow + k0);
#pragma unroll
        for (int n = 0; n < NT; ++n) {
            bf16x8 b = *(const bf16x8*)(Wt + (size_t)(n * 16 + m) * K + k0 + kg * 8);
            acc[n] = __builtin_amdgcn_mfma_f32_16x16x32_bf16(a, b, acc[n], 0, 0, 0);
        }
    }

    const int orow = row0 + kg * 4;

    if (ATTN) {
        float sl[NHEADS][4], sr[NHEADS][4];
#pragma unroll
        for (int h = 0; h < NHEADS; ++h)
#pragma unroll
            for (int r = 0; r < 4; ++r) { sl[h][r] = 0.f; sr[h][r] = 0.f; }
#pragma unroll
        for (int n = 0; n < NT; ++n) {
            float alv = al[n * 16 + m];
            float arv = ar[n * 16 + m];
            const int h = n >> 2;
#pragma unroll
            for (int r = 0; r < 4; ++r) {
                sl[h][r] = fmaf(acc[n][r], alv, sl[h][r]);
                sr[h][r] = fmaf(acc[n][r], arv, sr[h][r]);
            }
        }
#pragma unroll
        for (int off = 1; off < 16; off <<= 1) {
#pragma unroll
            for (int h = 0; h < NHEADS; ++h)
#pragma unroll
                for (int r = 0; r < 4; ++r) {
                    sl[h][r] += __shfl_xor(sl[h][r], off);
                    sr[h][r] += __shfl_xor(sr[h][r], off);
                }
        }
#pragma unroll
        for (int r = 0; r < 4; ++r) {
            int gr = orow + r;
            if (gr < nrows) {
#pragma unroll
                for (int n = 0; n < NT; ++n)
                    zb[(size_t)gr * N + n * 16 + m] = f2bf(acc[n][r]);
                if (m == 0) {
                    *(float4*)(el4 + (size_t)gr * 4) = make_float4(sl[0][r], sl[1][r], sl[2][r], 0.f);
                    *(float4*)(er4 + (size_t)gr * 4) = make_float4(sr[0][r], sr[1][r], sr[2][r], 0.f);
                }
            }
        }
    } else {
#pragma unroll
        for (int r = 0; r < 4; ++r) {
            int gr = orow + r;
            if (gr < nrows) {
#pragma unroll
                for (int n = 0; n < NT; ++n)
                    xb[(size_t)gr * N + n * 16 + m] = f2bf(acc[n][r] + bias[n * 16 + m]);
            }
        }
    }
}

// ---------------- CSR build ----------------
// count: 4 edges/thread (independent atomic chains); store rank = old count.
__global__ __launch_bounds__(256) void count_kernel(const int* __restrict__ dst,
                                                    int* __restrict__ cnt,
                                                    int* __restrict__ rank) {
    int e0 = blockIdx.x * 1024 + threadIdx.x;
#pragma unroll
    for (int k = 0; k < 4; ++k) {
        int e = e0 + k * 256;
        if (e < NE) rank[e] = atomicAdd(&cnt[dst[e]], 1);
    }
}

__global__ __launch_bounds__(256) void scan_block_kernel(const int* __restrict__ cnt,
                                                         int* __restrict__ incl,
                                                         int* __restrict__ bsum, int n) {
    __shared__ int s[256];
    int tid = threadIdx.x;
    int i = blockIdx.x * 256 + tid;
    int v = (i < n) ? cnt[i] : 0;
    s[tid] = v;
    __syncthreads();
#pragma unroll
    for (int off = 1; off < 256; off <<= 1) {
        int add = (tid >= off) ? s[tid - off] : 0;
        __syncthreads();
        s[tid] += add;
        __syncthreads();
    }
    if (i < n) incl[i] = s[tid];
    if (tid == 255) bsum[blockIdx.x] = s[255];
}

// finalize: per-block exclusive prefix of bsum via wave-strided reduce + butterfly.
__global__ __launch_bounds__(256) void finalize_rowptr_kernel(const int* __restrict__ incl,
                                                              const int* __restrict__ bsum,
                                                              int* __restrict__ row_ptr, int n) {
    int b = blockIdx.x;
    int part = 0;
    for (int k = (threadIdx.x & 63); k < b; k += 64) part += bsum[k];
#pragma unroll
    for (int off = 32; off > 0; off >>= 1) part += __shfl_xor(part, off);
    int i = b * 256 + threadIdx.x;
    if (i < n) row_ptr[i + 1] = incl[i] + part;
    if (i == 0) row_ptr[0] = 0;
}

// fill: atomic-free scatter using precomputed rank.
__global__ __launch_bounds__(256) void fill_kernel(const int* __restrict__ src,
                                                   const int* __restrict__ dst,
                                                   const int* __restrict__ row_ptr,
                                                   const int* __restrict__ rank,
                                                   int* __restrict__ srcs_sorted) {
    int e = blockIdx.x * 256 + threadIdx.x;
    if (e < NE) {
        srcs_sorted[row_ptr[dst[e]] + rank[e]] = src[e];
    }
}

// ---------------- aggregation: one wave per dst node, single pass, 8-deep MLP ----------------
// Chunk prologue (all 64 lanes): lane i computes exp-scores for edge c0+i, accumulates
// denom, writes p to wave-local padded LDS plds[wid][3][72] (rows 16B-aligned, 8 banks apart).
// Inner loop (lanes 0..47, 8 edges/iter): 8 independent gathers issued before any use.
__global__ __launch_bounds__(256) void aggregate_kernel(const ushort_t* __restrict__ zb,
                                                        const float* __restrict__ el4,
                                                        const float* __restrict__ er4,
                                                        const int* __restrict__ row_ptr,
                                                        const int* __restrict__ srcs,
                                                        const float* __restrict__ bias,
                                                        ushort_t* __restrict__ yb) {
    __shared__ float plds[4][NHEADS][72];
    int node = blockIdx.x * 4 + (threadIdx.x >> 6);
    int lane = threadIdx.x & 63;
    if (node >= NN) return;
    int s0 = row_ptr[node], s1 = row_ptr[node + 1];
    size_t o = (size_t)node * HD;
    const int wid = threadIdx.x >> 6;
    const int h = lane >> 4;    // head for owned dims (lanes 0..47)
    const int loff = lane * 4;  // ushort offset (8B per lane)

    float4 erv = *(const float4*)(er4 + (size_t)node * 4);

    float d0 = 0.f, d1 = 0.f, d2 = 0.f;
    f32x4 a = {0.f, 0.f, 0.f, 0.f};

    for (int c0 = s0; c0 < s1; c0 += 64) {
        int i = c0 + lane;
        float p0 = 0.f, p1 = 0.f, p2 = 0.f;
        int s = 0;
        if (i < s1) {
            s = srcs[i];
            float4 elv = *(const float4*)(el4 + (size_t)s * 4);
            float e0 = elv.x + erv.x, e1 = elv.y + erv.y, e2 = elv.z + erv.z;
            e0 = e0 > 0.f ? e0 : 0.2f * e0;
            e1 = e1 > 0.f ? e1 : 0.2f * e1;
            e2 = e2 > 0.f ? e2 : 0.2f * e2;
            p0 = __expf(fminf(e0, 60.f));
            p1 = __expf(fminf(e1, 60.f));
            p2 = __expf(fminf(e2, 60.f));
        }
        d0 += p0; d1 += p1; d2 += p2;
        plds[wid][0][lane] = p0;
        plds[wid][1][lane] = p1;
        plds[wid][2][lane] = p2;
        // wave-local LDS: order write->read within the wave (no __syncthreads;
        // divergent per-wave loop). The waitcnt drains the ds_writes.
        asm volatile("s_waitcnt lgkmcnt(0)" ::: "memory");
        int nch = s1 - c0; if (nch > 64) nch = 64;
        if (lane < 48) {
            const float* prow = &plds[wid][h][0];
            for (int j = 0; j < nch; j += 8) {
                ushort4 zv[8];
#pragma unroll
                for (int t = 0; t < 8; ++t) {
                    int sj = __builtin_amdgcn_readlane(s, j + t);
                    zv[t] = *(const ushort4*)(zb + (size_t)sj * HD + loff);
                }
                float4 qa = *(const float4*)(prow + j);       // ds_read_b128
                float4 qb = *(const float4*)(prow + j + 4);
                float qq[8] = {qa.x, qa.y, qa.z, qa.w, qb.x, qb.y, qb.z, qb.w};
#pragma unroll
                for (int t = 0; t < 8; ++t) {
                    a[0] = fmaf(qq[t], bf2f(zv[t].x), a[0]);
                    a[1] = fmaf(qq[t], bf2f(zv[t].y), a[1]);
                    a[2] = fmaf(qq[t], bf2f(zv[t].z), a[2]);
                    a[3] = fmaf(qq[t], bf2f(zv[t].w), a[3]);
                }
            }
        }
    }
#pragma unroll
    for (int off = 32; off > 0; off >>= 1) {
        d0 += __shfl_xor(d0, off);
        d1 += __shfl_xor(d1, off);
        d2 += __shfl_xor(d2, off);
    }

    if (lane < 48) {
        float dd = (h == 0) ? d0 : ((h == 1) ? d1 : d2);
        float rinv = 1.0f / dd;
        float4 bb = *(const float4*)(bias + loff);
        ushort4 ov;
        ov.x = f2bf(a[0] * rinv + bb.x);
        ov.y = f2bf(a[1] * rinv + bb.y);
        ov.z = f2bf(a[2] * rinv + bb.z);
        ov.w = f2bf(a[3] * rinv + bb.w);
        *(ushort4*)(yb + o + loff) = ov;
    }
}

// ---------------- pooling (reads bf16 x) ----------------
__global__ __launch_bounds__(256) void pool_kernel(const ushort_t* __restrict__ xb,
                                                   const int* __restrict__ gid,
                                                   float* __restrict__ gsum,
                                                   int* __restrict__ gcnt) {
    int w = blockIdx.x * 4 + (threadIdx.x >> 6);
    int lane = threadIdx.x & 63;
    int n0 = w * 16;
    if (n0 >= NN) return;
    int n1 = n0 + 16; if (n1 > NN) n1 = NN;
    int curg = gid[n0];
    float acc = 0.f;
    int cl = 0;
    for (int n = n0; n < n1; ++n) {
        int g = gid[n];
        if (g != curg) {
            atomicAdd(&gsum[curg * 64 + lane], acc);
            if (lane == 0) atomicAdd(&gcnt[curg], cl);
            acc = 0.f; cl = 0; curg = g;
        }
        acc += bf2f(xb[(size_t)n * 64 + lane]);
        cl++;
    }
    atomicAdd(&gsum[curg * 64 + lane], acc);
    if (lane == 0) atomicAdd(&gcnt[curg], cl);
}

__global__ __launch_bounds__(256) void pool_final_kernel(const float* __restrict__ gsum,
                                                         const int* __restrict__ gcnt,
                                                         float* __restrict__ out) {
    int idx = blockIdx.x * 256 + threadIdx.x;
    if (idx < NG * 64) {
        int g = idx >> 6;
        float c = (float)gcnt[g];
        out[idx] = gsum[idx] / fmaxf(c, 1.0f);
    }
}

// ---------------- launch ----------------
extern "C" void kernel_launch(void* const* d_in, const int* in_sizes, int n_in,
                              void* d_out, int out_size, void* d_ws, size_t ws_size,
                              hipStream_t stream) {
    const float* feats = (const float*)d_in[0];
    const int* src = (const int*)d_in[1];
    const int* dst = (const int*)d_in[2];
    const int* gid = (const int*)d_in[3];
    const float* W1 = (const float*)d_in[4];
    const float* al1 = (const float*)d_in[5];
    const float* ar1 = (const float*)d_in[6];
    const float* b1 = (const float*)d_in[7];
    const float* W2 = (const float*)d_in[8];
    const float* al2 = (const float*)d_in[9];
    const float* ar2 = (const float*)d_in[10];
    const float* b2 = (const float*)d_in[11];
    const float* Wl = (const float*)d_in[12];
    const float* bl = (const float*)d_in[13];
    float* out = (float*)d_out;

    size_t off = 0;
    auto alloc = [&](size_t bytes) -> char* {
        char* p = (char*)d_ws + off;
        off += (bytes + 255) & ~(size_t)255;
        return p;
    };
    ushort_t* featsb = (ushort_t*)alloc((size_t)NN * FIN * 2);
    ushort_t* zb = (ushort_t*)alloc((size_t)NN * HD * 2);
    ushort_t* yb = (ushort_t*)alloc((size_t)NN * HD * 2);
    ushort_t* xb = (ushort_t*)alloc((size_t)NN * 64 * 2);
    float* el4 = (float*)alloc((size_t)NN * 4 * 4);
    float* er4 = (float*)alloc((size_t)NN * 4 * 4);
    ushort_t* W1t = (ushort_t*)alloc((size_t)HD * FIN * 2);  // [192][128]
    ushort_t* W2t = (ushort_t*)alloc((size_t)HD * 64 * 2);   // [192][64]
    ushort_t* Wlt = (ushort_t*)alloc((size_t)64 * HD * 2);   // [64][192]
    int* row_ptr = (int*)alloc((size_t)(NN + 1) * 4);
    int* cnt = (int*)alloc((size_t)NN * 4);
    int* incl = (int*)alloc((size_t)NN * 4);
    int* bsum = (int*)alloc(256 * 4);
    int* rank = (int*)alloc((size_t)NE * 4);
    int* srcs = (int*)alloc((size_t)NE * 4);
    float* gsum = (float*)alloc((size_t)NG * 64 * 4);
    int* gcnt = (int*)alloc((size_t)NG * 4);

    const int nbScan = (NN + 255) / 256;
    const int gridE = (NE + 255) / 256;
    const int gridNode = (NN + 3) / 4;
    const int gridGemm = (NN + 63) / 64;

    // ---- fused input conversions ----
    conv_all_kernel<<<(F4 + W1E + W2E + WLE + 255) / 256, 256, 0, stream>>>(
        feats, W1, W2, Wl, featsb, W1t, W2t, Wlt);

    // ---- CSR build (shared by all 3 convs) ----
    hipMemsetAsync(cnt, 0, (size_t)NN * 4, stream);
    count_kernel<<<(NE + 1023) / 1024, 256, 0, stream>>>(dst, cnt, rank);
    scan_block_kernel<<<nbScan, 256, 0, stream>>>(cnt, incl, bsum, NN);
    finalize_rowptr_kernel<<<nbScan, 256, 0, stream>>>(incl, bsum, row_ptr, NN);
    fill_kernel<<<gridE, 256, 0, stream>>>(src, dst, row_ptr, rank, srcs);

    // ---- conv1 ----
    mgemm_kernel<FIN, 12, 1><<<gridGemm, 256, 0, stream>>>(featsb, W1t, nullptr, al1, ar1,
                                                           el4, er4, nullptr, zb, NN);
    aggregate_kernel<<<gridNode, 256, 0, stream>>>(zb, el4, er4, row_ptr, srcs, b1, yb);
    mgemm_kernel<HD, 4, 0><<<gridGemm, 256, 0, stream>>>(yb, Wlt, bl, nullptr, nullptr,
                                                         nullptr, nullptr, xb, nullptr, NN);

    // ---- conv2, conv3 ----
    for (int it = 0; it < 2; ++it) {
        mgemm_kernel<64, 12, 1><<<gridGemm, 256, 0, stream>>>(xb, W2t, nullptr, al2, ar2,
                                                              el4, er4, nullptr, zb, NN);
        aggregate_kernel<<<gridNode, 256, 0, stream>>>(zb, el4, er4, row_ptr, srcs, b2, yb);
        mgemm_kernel<HD, 4, 0><<<gridGemm, 256, 0, stream>>>(yb, Wlt, bl, nullptr, nullptr,
                                                             nullptr, nullptr, xb, nullptr, NN);
    }

    // ---- avg pooling ----
    hipMemsetAsync(gsum, 0, (size_t)NG * 64 * 4 + (size_t)NG * 4, stream);
    pool_kernel<<<(NN / 16 + 3) / 4 + 1, 256, 0, stream>>>(xb, gid, gsum, gcnt);
    pool_final_kernel<<<(NG * 64 + 255) / 256, 256, 0, stream>>>(gsum, gcnt, out);
}